// Round 11
// baseline (458.849 us; speedup 1.0000x reference)
//
#include <hip/hip_runtime.h>
#include <math.h>

typedef unsigned short u16;
typedef unsigned int u32;
typedef __bf16 bf16x8 __attribute__((ext_vector_type(8)));
typedef float f32x4 __attribute__((ext_vector_type(4)));

#define NPQ 512
#define MNP 4096
#define BSZ 8
#define DIM 256
#define NH 8
#define HD 32
#define TOPK 32
#define FFD 2048
#define SCALE 0.17677669529663687f  // 1/sqrt(32)

__device__ __forceinline__ u16 f2bf(float f){
  u32 u = __builtin_bit_cast(u32, f);
  u = (u + 0x7FFFu + ((u >> 16) & 1u)) >> 16;
  return (u16)u;
}
__device__ __forceinline__ float bf2f(u16 h){
  u32 u = ((u32)h) << 16;
  return __builtin_bit_cast(float, u);
}
__device__ __forceinline__ float wredsum(float v){
#pragma unroll
  for (int m = 32; m; m >>= 1) v += __shfl_xor(v, m, 64);
  return v;
}
__device__ __forceinline__ float gelu_exact(float x){
  return 0.5f * x * (1.0f + erff(x * 0.70710678118654752f));
}
__device__ __forceinline__ u32 keytr(u32 u){
  return u ^ (((u32)((int)u >> 31)) | 0x80000000u);
}

// ---------------- fused prep: prep_mem | prep_tgt | cvt_all --------------
#define FP_MEM_B 32768
#define FP_TGT_B (32768 + 4096)
#define FP_TOT_B (32768 + 4096 + 5888)
__global__ __launch_bounds__(256)
void fused_prep(const float* __restrict__ mem, const float* __restrict__ kpos,
                u16* __restrict__ mnh, u16* __restrict__ mnl,
                u16* __restrict__ kc, u16* __restrict__ vc,
                const float* __restrict__ tgt, const float* __restrict__ qpos,
                u16* __restrict__ xnh, u16* __restrict__ xnl, u16* __restrict__ qc,
                const float* __restrict__ cb2, const float* __restrict__ cb3,
                float* __restrict__ cbKV,
                const float* __restrict__ s0, const float* __restrict__ s1,
                const float* __restrict__ s2, const float* __restrict__ s3,
                const float* __restrict__ s4, const float* __restrict__ s5,
                const float* __restrict__ s6, u16* __restrict__ wdst){
  __shared__ float sc[4];
  int gb = blockIdx.x, t = threadIdx.x;
  if (gb < FP_MEM_B){
    int r = gb;
    int b = r >> 12, mp = r & 4095;
    long src = ((long)mp*BSZ + b)*DIM + t;
    float x = mem[src];
    float s = wredsum(x*x);
    if ((t & 63) == 0) sc[t >> 6] = s;
    __syncthreads();
    float tot = sc[0]+sc[1]+sc[2]+sc[3];
    float xn = x / sqrtf(tot);
    u16 hi = f2bf(xn);
    long dst = (long)r*DIM + t;
    mnh[dst] = hi;
    mnl[dst] = f2bf(xn - bf2f(hi));
    kc[dst]  = f2bf(x + kpos[src]);
    vc[dst]  = f2bf(x);
  } else if (gb < FP_TGT_B){
    int r = gb - FP_MEM_B;
    if (r == 0){ cbKV[t] = cb2[t]; cbKV[256 + t] = cb3[t]; }
    int b = r >> 9, n = r & 511;
    long src = ((long)n*BSZ + b)*DIM + t;
    float x = tgt[src];
    float s = wredsum(x*x);
    if ((t & 63) == 0) sc[t >> 6] = s;
    __syncthreads();
    float tot = sc[0]+sc[1]+sc[2]+sc[3];
    float xn = x / sqrtf(tot);
    u16 hi = f2bf(xn);
    long dst = (long)r*DIM + t;
    xnh[dst] = hi;
    xnl[dst] = f2bf(xn - bf2f(hi));
    qc[dst]  = f2bf(x + qpos[src]);
  } else {
    int i = (gb - FP_TGT_B)*256 + t;
    if (i >= 1507328) return;
    const float* s; int base;
    if      (i <  65536){ s = s0; base = 0; }
    else if (i < 131072){ s = s1; base = 65536; }
    else if (i < 196608){ s = s2; base = 131072; }
    else if (i < 393216){ s = s3; base = 196608; }
    else if (i < 458752){ s = s4; base = 393216; }
    else if (i < 983040){ s = s5; base = 458752; }
    else                { s = s6; base = 983040; }
    wdst[i] = f2bf(s[i - base]);
  }
}

// ---------------- sim GEMM (split bf16, LDS-staged B) ----------------
// R7: R2 structure (BK=128, BST=136, (256,2), in-wave A prefetch) -- the
// proven-fastest clean version (~50us, VGPR 116, no spill). Do NOT retry:
// (256,4)/BK=64 (acc spill), (256,3)/BK=64 (neutral), T14 reg-stage
// (staging spill). Compiler lesson: aggregates live across __syncthreads
// at 256 threads get spilled.
#define BST 136
__global__ __launch_bounds__(256, 2)
void sim_gemm(const u16* __restrict__ xnh, const u16* __restrict__ xnl,
              const u16* __restrict__ mnh, const u16* __restrict__ mnl,
              float* __restrict__ sim){
  __shared__ __align__(16) u16 Bh[128*BST];
  __shared__ __align__(16) u16 Bl[128*BST];
  int t = threadIdx.x, lane = t & 63, wv = t >> 6;
  int ml = lane & 15, quad = lane >> 4;
  int b = blockIdx.z;
  int tM = blockIdx.y * 128 + (wv & 1) * 64;
  int tN = blockIdx.x * 128;
  int nloc = (wv >> 1) * 64;
  const u16* Ah = xnh + ((long)b*NPQ + tM + ml)*DIM;
  const u16* Al = xnl + ((long)b*NPQ + tM + ml)*DIM;
  f32x4 acc[4][4];
  f32x4 zer = {0.f,0.f,0.f,0.f};
#pragma unroll
  for (int i = 0; i < 4; i++)
#pragma unroll
    for (int j = 0; j < 4; j++) acc[i][j] = zer;

  int srow = t >> 4, scg = t & 15;
  for (int half = 0; half < 2; half++){
    int k0 = half * 128;
    if (half) __syncthreads();
#pragma unroll
    for (int p = 0; p < 8; p++){
      int r = p*16 + srow;
      long g = ((long)b*MNP + tN + r)*DIM + k0 + scg*8;
      *(uint4*)(&Bh[r*BST + scg*8]) = *(const uint4*)(mnh + g);
      *(uint4*)(&Bl[r*BST + scg*8]) = *(const uint4*)(mnl + g);
    }
    bf16x8 ca[4], ca2[4], na[4], na2[4];
#pragma unroll
    for (int i = 0; i < 4; i++){
      ca[i]  = *(const bf16x8*)(Ah + (long)i*16*DIM + k0 + quad*8);
      ca2[i] = *(const bf16x8*)(Al + (long)i*16*DIM + k0 + quad*8);
    }
    __syncthreads();
#pragma unroll
    for (int kk = 0; kk < 128; kk += 32){
      if (kk < 96){
#pragma unroll
        for (int i = 0; i < 4; i++){
          na[i]  = *(const bf16x8*)(Ah + (long)i*16*DIM + k0 + kk + 32 + quad*8);
          na2[i] = *(const bf16x8*)(Al + (long)i*16*DIM + k0 + kk + 32 + quad*8);
        }
      }
      bf16x8 bh[4], bl[4];
#pragma unroll
      for (int j = 0; j < 4; j++){
        int nr = nloc + j*16 + ml;
        bh[j] = *(const bf16x8*)(&Bh[nr*BST + kk + quad*8]);
        bl[j] = *(const bf16x8*)(&Bl[nr*BST + kk + quad*8]);
      }
#pragma unroll
      for (int i = 0; i < 4; i++)
#pragma unroll
        for (int j = 0; j < 4; j++){
          acc[i][j] = __builtin_amdgcn_mfma_f32_16x16x32_bf16(ca[i],  bh[j], acc[i][j], 0, 0, 0);
          acc[i][j] = __builtin_amdgcn_mfma_f32_16x16x32_bf16(ca[i],  bl[j], acc[i][j], 0, 0, 0);
          acc[i][j] = __builtin_amdgcn_mfma_f32_16x16x32_bf16(ca2[i], bh[j], acc[i][j], 0, 0, 0);
        }
#pragma unroll
      for (int i = 0; i < 4; i++){ ca[i] = na[i]; ca2[i] = na2[i]; }
    }
  }
  long zC = (long)b * NPQ * MNP;
#pragma unroll
  for (int i = 0; i < 4; i++)
#pragma unroll
    for (int r = 0; r < 4; r++){
      int row = tM + i*16 + quad*4 + r;
#pragma unroll
      for (int j = 0; j < 4; j++){
        int col = tN + nloc + j*16 + ml;
        sim[zC + (long)row*MNP + col] = acc[i][j][r];
      }
    }
}

// ---------------- projection GEMM ----------------
#define PBST 264
template<int KGROUPS, int OUT_BF16, int ACT>
__global__ __launch_bounds__(256)
void pgemm(const u16* __restrict__ A, const u16* __restrict__ A2, int selCol,
           const u16* __restrict__ B, const float* __restrict__ bias,
           void* __restrict__ Cv, int N){
  __shared__ __align__(16) u16 Bs[64*PBST];
  const int K = KGROUPS*256;
  int t = threadIdx.x, lane = t & 63, wv = t >> 6;
  int ml = lane & 15, quad = lane >> 4;
  int tM = blockIdx.x*64;
  int tN = blockIdx.y*64;
  const u16* Ab = (tN < selCol) ? A : A2;
  const u16* Arow = Ab + (long)(tM + wv*16 + ml)*K;
  f32x4 acc[4];
  f32x4 zer = {0.f,0.f,0.f,0.f};
#pragma unroll
  for (int nj = 0; nj < 4; nj++) acc[nj] = zer;
  int srow = t >> 5, scol = (t & 31)*8;
  for (int g = 0; g < KGROUPS; g++){
    if (g) __syncthreads();
#pragma unroll
    for (int p = 0; p < 8; p++){
      int r = p*8 + srow;
      *(uint4*)(&Bs[r*PBST + scol]) = *(const uint4*)(B + (long)(tN + r)*K + g*256 + scol);
    }
    bf16x8 a[8];
#pragma unroll
    for (int kk = 0; kk < 8; kk++)
      a[kk] = *(const bf16x8*)(Arow + g*256 + kk*32 + quad*8);
    __syncthreads();
#pragma unroll
    for (int kk = 0; kk < 8; kk++){
#pragma unroll
      for (int nj = 0; nj < 4; nj++){
        bf16x8 bv = *(const bf16x8*)(&Bs[(nj*16 + ml)*PBST + kk*32 + quad*8]);
        acc[nj] = __builtin_amdgcn_mfma_f32_16x16x32_bf16(a[kk], bv, acc[nj], 0, 0, 0);
      }
    }
  }
#pragma unroll
  for (int nj = 0; nj < 4; nj++){
    int col = tN + nj*16 + ml;
    float bv = bias[col];
#pragma unroll
    for (int r = 0; r < 4; r++){
      int row = tM + wv*16 + quad*4 + r;
      float v = acc[nj][r] + bv;
      if (ACT == 1) v = gelu_exact(v);
      long idx = (long)row * N + col;
      if (OUT_BF16) ((u16*)Cv)[idx] = f2bf(v);
      else ((float*)Cv)[idx] = v;
    }
  }
}

// ---------------- top-k: 8-bit radix-select, wave-aggregated atomics -----
// R11: match-any ballot aggregation. Diagnosis chain: radix topk ~40us
// (totals reconciliation R7-R9) with SQ_LDS_BANK_CONFLICT=7.4M (R9).
// Round 0's 4096 keys/block cluster into ~6-10 exponent-byte bins -> each
// atomicAdd instr has ~64 lanes on the SAME LDS address = 64-deep
// serialization WITHIN the instruction (R8's per-wave copies couldn't fix
// intra-wave contention; measured neutral). Fix: per key-slot, loop over
// distinct digits present in the wave (ballot/shfl); ONE leader lane does
// atomicAdd(digit, popcount(match)). Round 0: ~8 iters/slot replacing
// 64-way serialization; rounds 1-3: predicate sparse -> 0-2 iters.
// Histogram counts bit-identical -> selection/ties/emission unchanged.
#define HSTRIDE 264
__global__ __launch_bounds__(256, 4)
void topk_k(const float* __restrict__ sim, int* __restrict__ rns){
  __shared__ int hist[4*HSTRIDE];
  __shared__ int sh_B, sh_above;
  __shared__ int scnt, stcnt;
  __shared__ int sties[256];
  int t = threadIdx.x, wv = t >> 6, lane = t & 63;
  long r = blockIdx.x;
  const uint4* row4 = (const uint4*)(sim + r*4096);
  u32 key[16];
#pragma unroll
  for (int j = 0; j < 4; j++){
    uint4 v = row4[j*256 + t];
    key[j*4+0] = keytr(v.x);
    key[j*4+1] = keytr(v.y);
    key[j*4+2] = keytr(v.z);
    key[j*4+3] = keytr(v.w);
  }
#pragma unroll
  for (int i = 0; i < 16; i++) asm volatile("" : "+v"(key[i]));
  if (t == 0){ scnt = 0; stcnt = 0; }
  u32 pref = 0;
  int k_above = 0;
#pragma unroll 1
  for (int round = 0; round < 4; round++){
    int shift = 24 - round*8;
    u32 pmask = (round == 0) ? 0u : (0xFFFFFFFFu << (shift + 8));
    for (int z = t; z < 4*HSTRIDE; z += 256) hist[z] = 0;
    __syncthreads();
    int* myh = hist + wv*HSTRIDE;
#pragma unroll 1
    for (int i = 0; i < 16; i++){
      bool pred = ((key[i] ^ pref) & pmask) == 0;
      u32 d = (key[i] >> shift) & 255;
      unsigned long long todo = __ballot(pred);
      while (todo){
        int src = (int)__builtin_ctzll(todo);
        u32 dd = __shfl(d, src, 64);
        unsigned long long match = __ballot(pred && d == dd);
        if (lane == src) atomicAdd(&myh[dd], (int)__popcll(match));
        todo &= ~match;
      }
    }
    __syncthreads();
    if (t < 64){
      int b0 = t*4+0, b1 = t*4+1, b2 = t*4+2, b3 = t*4+3;
      int h0 = hist[b0] + hist[HSTRIDE+b0] + hist[2*HSTRIDE+b0] + hist[3*HSTRIDE+b0];
      int h1 = hist[b1] + hist[HSTRIDE+b1] + hist[2*HSTRIDE+b1] + hist[3*HSTRIDE+b1];
      int h2 = hist[b2] + hist[HSTRIDE+b2] + hist[2*HSTRIDE+b2] + hist[3*HSTRIDE+b2];
      int h3 = hist[b3] + hist[HSTRIDE+b3] + hist[2*HSTRIDE+b3] + hist[3*HSTRIDE+b3];
      int local = h0 + h1 + h2 + h3;
      int s = local;
#pragma unroll
      for (int off = 1; off < 64; off <<= 1){
        int v = __shfl_down(s, off, 64);
        s += (t + off < 64) ? v : 0;
      }
      int excl = s - local;            // sum of hist over lanes > t
      int a3 = excl, a2 = a3 + h3, a1 = a2 + h2, a0 = a1 + h1;
      int ka = k_above;
      if (ka + a3 < TOPK && ka + a3 + h3 >= TOPK){ sh_B = t*4+3; sh_above = ka + a3; }
      if (ka + a2 < TOPK && ka + a2 + h2 >= TOPK){ sh_B = t*4+2; sh_above = ka + a2; }
      if (ka + a1 < TOPK && ka + a1 + h1 >= TOPK){ sh_B = t*4+1; sh_above = ka + a1; }
      if (ka + a0 < TOPK && ka + a0 + h0 >= TOPK){ sh_B = t*4+0; sh_above = ka + a0; }
    }
    __syncthreads();
    pref |= ((u32)sh_B) << shift;
    k_above = sh_above;
  }
  int* out = rns + r*32;
#pragma unroll
  for (int i = 0; i < 16; i++){
    int gidx = (i >> 2)*1024 + t*4 + (i & 3);
    u32 kk = key[i];
    if (kk > pref){
      int p = atomicAdd(&scnt, 1);
      out[p] = gidx;
    } else if (kk == pref){
      int p = atomicAdd(&stcnt, 1);
      if (p < 256) sties[p] = gidx;
    }
  }
  __syncthreads();
  if (t == 0){
    int n = stcnt; if (n > 256) n = 256;
    int k_rem = TOPK - k_above;   // >= 1 by construction
    for (int s = 0; s < k_rem; s++){
      int mb = 0;
      for (int j = 1; j < n; j++) if (sties[j] < sties[mb]) mb = j;
      out[k_above + s] = sties[mb];
      sties[mb] = 0x7FFFFFFF;
    }
  }
}

// ---------------- sparse gathered cross-attention ----------------
// khvh layout: [32768][512], K at col 0..255, V at col 256..511
#define CAS 272
__global__ __launch_bounds__(256)
void cross_attn(const u16* __restrict__ qh, const u16* __restrict__ khvh,
                const int* __restrict__ rns, float* __restrict__ crossO){
  __shared__ __align__(16) u16 Kg[32*CAS];
  __shared__ __align__(16) u16 Vg[32*CAS];
  __shared__ float qv[256];
  __shared__ int idxs[32];
  __shared__ float L[256];
  __shared__ float pm[8], ps[8];
  int r = blockIdx.x, t = threadIdx.x;
  int b = r >> 9;
  if (t < 32) idxs[t] = rns[(long)r*32 + t];
  qv[t] = bf2f(qh[(long)r*DIM + t]);
  __syncthreads();
  for (int i = t; i < 32*64; i += 256){
    int k = i >> 6, c = (i & 63) * 4;
    long src = ((long)b*MNP + idxs[k])*512 + c;
    *(ushort4*)(&Kg[k*CAS + c]) = *(const ushort4*)(khvh + src);
    *(ushort4*)(&Vg[k*CAS + c]) = *(const ushort4*)(khvh + src + 256);
  }
  __syncthreads();
  {
    int h = t >> 5, k = t & 31;
    float acc = 0.f;
#pragma unroll
    for (int d = 0; d < 32; d++) acc += qv[h*HD + d] * bf2f(Kg[k*CAS + h*HD + d]);
    L[t] = acc * SCALE;
  }
  __syncthreads();
  if (t < 8){
    float m = L[t*32];
    for (int k = 1; k < 32; k++) m = fmaxf(m, L[t*32 + k]);
    float s = 0.f;
    for (int k = 0; k < 32; k++) s += expf(L[t*32 + k] - m);
    pm[t] = m; ps[t] = s;
  }
  __syncthreads();
  {
    int h = t >> 5, dd = t & 31;
    float m = pm[h], inv = 1.0f/ps[h], acc = 0.f;
#pragma unroll
    for (int k = 0; k < 32; k++) acc += expf(L[h*32 + k] - m) * bf2f(Vg[k*CAS + h*HD + dd]);
    crossO[(long)r*DIM + t] = acc * inv;
  }
}

// ---------------- fused layernorms ----------------
template<int MODE>
__global__ __launch_bounds__(256)
void ln_k(const float* __restrict__ xa, const float* __restrict__ xb,
          const float* __restrict__ qpos,
          const float* __restrict__ w, const float* __restrict__ bsh,
          float* __restrict__ yf, u16* __restrict__ yb, u16* __restrict__ qkb){
  __shared__ float sc[8];
  int r = blockIdx.x, t = threadIdx.x;
  int b = r >> 9, n = r & 511;
  long bidx = (long)r*DIM + t;
  long nidx = ((long)n*BSZ + b)*DIM + t;
  float x = (MODE == 1 ? xa[nidx] : xa[bidx]) + xb[bidx];
  float s  = wredsum(x);
  float s2 = wredsum(x*x);
  int wv = t >> 6;
  if ((t & 63) == 0){ sc[wv] = s; sc[4 + wv] = s2; }
  __syncthreads();
  float S  = sc[0]+sc[1]+sc[2]+sc[3];
  float S2 = sc[4]+sc[5]+sc[6]+sc[7];
  float mu  = S * (1.f/256.f);
  float var = S2 * (1.f/256.f) - mu*mu;
  float y = (x - mu) * (1.0f / sqrtf(var + 1e-5f)) * w[t] + bsh[t];
  if (MODE == 3){
    yf[nidx] = y;
  } else {
    yf[bidx] = y;
    yb[bidx] = f2bf(y);
    if (MODE == 1) qkb[bidx] = f2bf(y + qpos[nidx]);
  }
}

// ---------------- fused dense self-attention (MFMA) ----------------
// qkv layout: [4096][768], q at 0, k at 256, v at 512.
#define KST 40
#define PST 264
__global__ __launch_bounds__(256)
void self_attn(const u16* __restrict__ qkv, u16* __restrict__ sa_pre){
  __shared__ __align__(16) u16 KS[512*KST];
  __shared__ __align__(16) u16 QS[32*KST];
  __shared__ float mbuf[128];
  __shared__ float sbuf[128];
  u16* P  = KS;
  u16* Vt = KS + 32*PST;

  int qt = blockIdx.x, h = blockIdx.y, b = blockIdx.z;
  int t = threadIdx.x, lane = t & 63, wv = t >> 6;
  int ml = lane & 15, quad = lane >> 4;
  int n0 = qt * 32;

  {
    int q = t >> 3, d4 = (t & 7) * 4;
    const u16* src = qkv + ((long)b*NPQ + n0 + q)*768 + h*HD + d4;
    *(ushort2*)(QS + q*KST + d4)     = *(const ushort2*)(src);
    *(ushort2*)(QS + q*KST + d4 + 2) = *(const ushort2*)(src + 2);
  }
  for (int i = t; i < 512*8; i += 256){
    int j = i >> 3, d4 = (i & 7) * 4;
    const u16* src = qkv + ((long)b*NPQ + j)*768 + 256 + h*HD + d4;
    *(ushort2*)(KS + j*KST + d4)     = *(const ushort2*)(src);
    *(ushort2*)(KS + j*KST + d4 + 2) = *(const ushort2*)(src + 2);
  }
  __syncthreads();

  f32x4 acc[2][8];
  {
    bf16x8 aq[2];
#pragma unroll
    for (int mi = 0; mi < 2; mi++)
      aq[mi] = *(const bf16x8*)(QS + (mi*16 + ml)*KST + quad*8);
#pragma unroll
    for (int nj = 0; nj < 8; nj++){
      bf16x8 bk = *(const bf16x8*)(KS + (wv*128 + nj*16 + ml)*KST + quad*8);
      f32x4 z = {0.f,0.f,0.f,0.f};
#pragma unroll
      for (int mi = 0; mi < 2; mi++)
        acc[mi][nj] = __builtin_amdgcn_mfma_f32_16x16x32_bf16(aq[mi], bk, z, 0, 0, 0);
    }
  }
  float lmax[2][4];
#pragma unroll
  for (int mi = 0; mi < 2; mi++)
#pragma unroll
    for (int r = 0; r < 4; r++) lmax[mi][r] = -3.4e38f;
#pragma unroll
  for (int mi = 0; mi < 2; mi++)
#pragma unroll
    for (int nj = 0; nj < 8; nj++)
#pragma unroll
      for (int r = 0; r < 4; r++){
        float v = acc[mi][nj][r] * SCALE;
        acc[mi][nj][r] = v;
        lmax[mi][r] = fmaxf(lmax[mi][r], v);
      }
#pragma unroll
  for (int m = 1; m < 16; m <<= 1)
#pragma unroll
    for (int mi = 0; mi < 2; mi++)
#pragma unroll
      for (int r = 0; r < 4; r++)
        lmax[mi][r] = fmaxf(lmax[mi][r], __shfl_xor(lmax[mi][r], m, 64));
  if (ml == 0){
#pragma unroll
    for (int mi = 0; mi < 2; mi++)
#pragma unroll
      for (int r = 0; r < 4; r++)
        mbuf[(mi*16 + quad*4 + r)*4 + wv] = lmax[mi][r];
  }
  __syncthreads();
  float inv_[2][4];
  float lsum[2][4];
#pragma unroll
  for (int mi = 0; mi < 2; mi++)
#pragma unroll
    for (int r = 0; r < 4; r++){
      int row = mi*16 + quad*4 + r;
      float m0 = fmaxf(fmaxf(mbuf[row*4+0], mbuf[row*4+1]),
                       fmaxf(mbuf[row*4+2], mbuf[row*4+3]));
      float s = 0.f;
#pragma unroll
      for (int nj = 0; nj < 8; nj++){
        float e = __expf(acc[mi][nj][r] - m0);
        acc[mi][nj][r] = e;
        s += e;
      }
      lsum[mi][r] = s;
    }
#pragma unroll
  for (int m = 1; m < 16; m <<= 1)
#pragma unroll
    for (int mi = 0; mi < 2; mi++)
#pragma unroll
      for (int r = 0; r < 4; r++)
        lsum[mi][r] += __shfl_xor(lsum[mi][r], m, 64);
  if (ml == 0){
#pragma unroll
    for (int mi = 0; mi < 2; mi++)
#pragma unroll
      for (int r = 0; r < 4; r++)
        sbuf[(mi*16 + quad*4 + r)*4 + wv] = lsum[mi][r];
  }
  __syncthreads();
#pragma unroll
  for (int mi = 0; mi < 2; mi++)
#pragma unroll
    for (int r = 0; r < 4; r++){
      int row = mi*16 + quad*4 + r;
      inv_[mi][r] = 1.0f / (sbuf[row*4+0]+sbuf[row*4+1]+sbuf[row*4+2]+sbuf[row*4+3]);
    }

  int mi2 = wv >> 1, ni = wv & 1;
  f32x4 acc2 = {0.f,0.f,0.f,0.f};
  for (int half = 0; half < 2; half++){
    __syncthreads();
    if ((wv >> 1) == half){
      int cbase = (wv & 1) * 128;
#pragma unroll
      for (int mi = 0; mi < 2; mi++)
#pragma unroll
        for (int nj = 0; nj < 8; nj++)
#pragma unroll
          for (int r = 0; r < 4; r++)
            P[(mi*16 + quad*4 + r)*PST + cbase + nj*16 + ml] = f2bf(acc[mi][nj][r]);
    }
    for (int i = t; i < 2048; i += 256){
      int j = i >> 3, d4 = (i & 7) * 4;
      const u16* src = qkv + ((long)b*NPQ + half*256 + j)*768 + 512 + h*HD + d4;
      u16 v0 = src[0], v1 = src[1], v2e = src[2], v3 = src[3];
      Vt[(d4+0)*PST + j] = v0;
      Vt[(d4+1)*PST + j] = v1;
      Vt[(d4+2)*PST + j] = v2e;
      Vt[(d4+3)*PST + j] = v3;
    }
    __syncthreads();
#pragma unroll
    for (int k0 = 0; k0 < 256; k0 += 32){
      bf16x8 ap = *(const bf16x8*)(P  + (mi2*16 + ml)*PST + k0 + quad*8);
      bf16x8 bv = *(const bf16x8*)(Vt + (ni*16  + ml)*PST + k0 + quad*8);
      acc2 = __builtin_amdgcn_mfma_f32_16x16x32_bf16(ap, bv, acc2, 0, 0, 0);
    }
  }
#pragma unroll
  for (int r = 0; r < 4; r++){
    int row = mi2*16 + quad*4 + r;
    sa_pre[((long)b*NPQ + n0 + row)*DIM + h*HD + ni*16 + ml] =
        f2bf(acc2[r] * inv_[mi2][r]);
  }
}

// =====================================================================
extern "C" void kernel_launch(void* const* d_in, const int* in_sizes, int n_in,
                              void* d_out, int out_size, void* d_ws, size_t ws_size,
                              hipStream_t stream){
  (void)in_sizes; (void)n_in; (void)out_size; (void)ws_size;
  const float* tgt  = (const float*)d_in[0];
  const float* mem  = (const float*)d_in[1];
  const float* qpos = (const float*)d_in[2];
  const float* kpos = (const float*)d_in[3];
  const float* cw1  = (const float*)d_in[4];  const float* cb1 = (const float*)d_in[5];
  const float* cw2  = (const float*)d_in[6];  const float* cb2 = (const float*)d_in[7];
  const float* cw3  = (const float*)d_in[8];  const float* cb3 = (const float*)d_in[9];
  const float* saw  = (const float*)d_in[10]; const float* sab = (const float*)d_in[11];
  const float* sow  = (const float*)d_in[12]; const float* sob = (const float*)d_in[13];
  const float* ln1w = (const float*)d_in[14]; const float* ln1b = (const float*)d_in[15];
  const float* ln2w = (const float*)d_in[16]; const float* ln2b = (const float*)d_in[17];
  const float* ln3w = (const float*)d_in[18]; const float* ln3b = (const float*)d_in[19];
  const float* f1w  = (const float*)d_in[20]; const float* f1bs = (const float*)d_in[21];
  const float* f2w  = (const float*)d_in[22]; const float* f2bs = (const float*)d_in[23];

  char* base = (char*)d_ws;
  size_t off = 0;
  auto alloc = [&](size_t bytes) -> char* {
    char* p = base + off;
    off += (bytes + 255) & ~(size_t)255;
    return p;
  };
  u16* cw1b = (u16*)alloc(65536u*2);
  u16* cw2b = (u16*)alloc(65536u*2);
  u16* cw3b = (u16*)alloc(65536u*2);   (void)cw3b;
  u16* sawb = (u16*)alloc(196608u*2);
  u16* sowb = (u16*)alloc(65536u*2);
  u16* f1wb = (u16*)alloc(524288u*2);
  u16* f2wb = (u16*)alloc(524288u*2);
  int* rns  = (int*)alloc(4096u*32*4);
  float* cbKV = (float*)alloc(512*4);
  size_t offB = off;
  u16* xnh = (u16*)alloc((size_t)4096*256*2);
  u16* xnl = (u16*)alloc((size_t)4096*256*2);
  u16* mnh = (u16*)alloc((size_t)32768*256*2);
  u16* mnl = (u16*)alloc((size_t)32768*256*2);
  u16* qc  = (u16*)alloc((size_t)4096*256*2);
  u16* kc  = (u16*)alloc((size_t)32768*256*2);
  u16* vc  = (u16*)alloc((size_t)32768*256*2);
  float* sim = (float*)alloc((size_t)8*512*4096*4);

  char* regC = (char*)sim;
  u16* qh   = (u16*)regC;                      // [4096][256]  2 MB
  u16* khvh = (u16*)(regC + 2097152);          // [32768][512] 32 MB
  char* regB = base + offB;
  size_t ob = 0;
  auto allocB = [&](size_t bytes) -> char* {
    char* p = regB + ob;
    ob += (bytes + 255) & ~(size_t)255;
    return p;
  };
  float* cross = (float*)allocB((size_t)4096*256*4);
  float* t1    = (float*)allocB((size_t)4096*256*4);
  u16*   t1b   = (u16*)allocB((size_t)4096*256*2);
  u16*   qkb   = (u16*)allocB((size_t)4096*256*2);
  u16*   qkv   = (u16*)allocB((size_t)4096*768*2);
  u16*   sa_pre= (u16*)allocB((size_t)4096*256*2);
  float* sa    = (float*)allocB((size_t)4096*256*4);
  float* t2    = (float*)allocB((size_t)4096*256*4);
  u16*   t2b   = (u16*)allocB((size_t)4096*256*2);
  u16*   h1    = (u16*)allocB((size_t)4096*2048*2);
  float* ff    = (float*)allocB((size_t)4096*256*4);

  const int BIG = 1 << 30;
  dim3 blk(256);
  fused_prep<<<dim3(FP_TOT_B), blk, 0, stream>>>(
      mem, kpos, mnh, mnl, kc, vc,
      tgt, qpos, xnh, xnl, qc, cb2, cb3, cbKV,
      cw1, cw2, cw3, saw, sow, f1w, f2w, cw1b);
  sim_gemm<<<dim3(32,4,8), blk, 0, stream>>>(xnh, xnl, mnh, mnl, sim);
  topk_k<<<dim3(4096), blk, 0, stream>>>(sim, rns);
  pgemm<1,1,0><<<dim3(64,4), blk, 0, stream>>>(qc, qc, BIG, cw1b, cb1, qh, 256);
  pgemm<1,1,0><<<dim3(512,8), blk, 0, stream>>>(kc, vc, 256, cw2b, cbKV, khvh, 512);
  cross_attn<<<dim3(4096), blk, 0, stream>>>(qh, khvh, rns, cross);
  ln_k<1><<<dim3(4096), blk, 0, stream>>>(tgt, cross, qpos, ln1w, ln1b, t1, t1b, qkb);
  pgemm<1,1,0><<<dim3(64,12), blk, 0, stream>>>(qkb, t1b, 512, sawb, sab, qkv, 768);
  self_attn<<<dim3(16,8,8), blk, 0, stream>>>(qkv, sa_pre);
  pgemm<1,0,0><<<dim3(64,4), blk, 0, stream>>>(sa_pre, sa_pre, BIG, sowb, sob, sa, 256);
  ln_k<2><<<dim3(4096), blk, 0, stream>>>(t1, sa, nullptr, ln2w, ln2b, t2, t2b, nullptr);
  pgemm<1,1,1><<<dim3(64,32), blk, 0, stream>>>(t2b, t2b, BIG, f1wb, f1bs, h1, 2048);
  pgemm<8,0,0><<<dim3(64,4), blk, 0, stream>>>(h1, h1, BIG, f2wb, f2bs, ff, 256);
  ln_k<3><<<dim3(4096), blk, 0, stream>>>(t2, ff, nullptr, ln3w, ln3b, (float*)d_out, nullptr, nullptr);
}

// Round 12
// 429.344 us; speedup vs baseline: 1.0687x; 1.0687x over previous
//
#include <hip/hip_runtime.h>
#include <math.h>

typedef unsigned short u16;
typedef unsigned int u32;
typedef __bf16 bf16x8 __attribute__((ext_vector_type(8)));
typedef float f32x4 __attribute__((ext_vector_type(4)));

#define NPQ 512
#define MNP 4096
#define BSZ 8
#define DIM 256
#define NH 8
#define HD 32
#define TOPK 32
#define FFD 2048
#define SCALE 0.17677669529663687f  // 1/sqrt(32)

__device__ __forceinline__ u16 f2bf(float f){
  u32 u = __builtin_bit_cast(u32, f);
  u = (u + 0x7FFFu + ((u >> 16) & 1u)) >> 16;
  return (u16)u;
}
__device__ __forceinline__ float bf2f(u16 h){
  u32 u = ((u32)h) << 16;
  return __builtin_bit_cast(float, u);
}
__device__ __forceinline__ float wredsum(float v){
#pragma unroll
  for (int m = 32; m; m >>= 1) v += __shfl_xor(v, m, 64);
  return v;
}
__device__ __forceinline__ float gelu_exact(float x){
  return 0.5f * x * (1.0f + erff(x * 0.70710678118654752f));
}
__device__ __forceinline__ u32 keytr(u32 u){
  return u ^ (((u32)((int)u >> 31)) | 0x80000000u);
}

// ---------------- fused prep: prep_mem | prep_tgt | cvt_all --------------
#define FP_MEM_B 32768
#define FP_TGT_B (32768 + 4096)
#define FP_TOT_B (32768 + 4096 + 5888)
__global__ __launch_bounds__(256)
void fused_prep(const float* __restrict__ mem, const float* __restrict__ kpos,
                u16* __restrict__ mnh, u16* __restrict__ mnl,
                u16* __restrict__ kc, u16* __restrict__ vc,
                const float* __restrict__ tgt, const float* __restrict__ qpos,
                u16* __restrict__ xnh, u16* __restrict__ xnl, u16* __restrict__ qc,
                const float* __restrict__ cb2, const float* __restrict__ cb3,
                float* __restrict__ cbKV,
                const float* __restrict__ s0, const float* __restrict__ s1,
                const float* __restrict__ s2, const float* __restrict__ s3,
                const float* __restrict__ s4, const float* __restrict__ s5,
                const float* __restrict__ s6, u16* __restrict__ wdst){
  __shared__ float sc[4];
  int gb = blockIdx.x, t = threadIdx.x;
  if (gb < FP_MEM_B){
    int r = gb;
    int b = r >> 12, mp = r & 4095;
    long src = ((long)mp*BSZ + b)*DIM + t;
    float x = mem[src];
    float s = wredsum(x*x);
    if ((t & 63) == 0) sc[t >> 6] = s;
    __syncthreads();
    float tot = sc[0]+sc[1]+sc[2]+sc[3];
    float xn = x / sqrtf(tot);
    u16 hi = f2bf(xn);
    long dst = (long)r*DIM + t;
    mnh[dst] = hi;
    mnl[dst] = f2bf(xn - bf2f(hi));
    kc[dst]  = f2bf(x + kpos[src]);
    vc[dst]  = f2bf(x);
  } else if (gb < FP_TGT_B){
    int r = gb - FP_MEM_B;
    if (r == 0){ cbKV[t] = cb2[t]; cbKV[256 + t] = cb3[t]; }
    int b = r >> 9, n = r & 511;
    long src = ((long)n*BSZ + b)*DIM + t;
    float x = tgt[src];
    float s = wredsum(x*x);
    if ((t & 63) == 0) sc[t >> 6] = s;
    __syncthreads();
    float tot = sc[0]+sc[1]+sc[2]+sc[3];
    float xn = x / sqrtf(tot);
    u16 hi = f2bf(xn);
    long dst = (long)r*DIM + t;
    xnh[dst] = hi;
    xnl[dst] = f2bf(xn - bf2f(hi));
    qc[dst]  = f2bf(x + qpos[src]);
  } else {
    int i = (gb - FP_TGT_B)*256 + t;
    if (i >= 1507328) return;
    const float* s; int base;
    if      (i <  65536){ s = s0; base = 0; }
    else if (i < 131072){ s = s1; base = 65536; }
    else if (i < 196608){ s = s2; base = 131072; }
    else if (i < 393216){ s = s3; base = 196608; }
    else if (i < 458752){ s = s4; base = 393216; }
    else if (i < 983040){ s = s5; base = 458752; }
    else                { s = s6; base = 983040; }
    wdst[i] = f2bf(s[i - base]);
  }
}

// ---------------- sim GEMM (split bf16, LDS-staged B) ----------------
// R7: R2 structure (BK=128, BST=136, (256,2), in-wave A prefetch) -- the
// proven-fastest clean version (~50us, VGPR 116, no spill). Do NOT retry:
// (256,4)/BK=64 (acc spill), (256,3)/BK=64 (neutral), T14 reg-stage
// (staging spill). Compiler lesson: aggregates live across __syncthreads
// at 256 threads get spilled.
#define BST 136
__global__ __launch_bounds__(256, 2)
void sim_gemm(const u16* __restrict__ xnh, const u16* __restrict__ xnl,
              const u16* __restrict__ mnh, const u16* __restrict__ mnl,
              float* __restrict__ sim){
  __shared__ __align__(16) u16 Bh[128*BST];
  __shared__ __align__(16) u16 Bl[128*BST];
  int t = threadIdx.x, lane = t & 63, wv = t >> 6;
  int ml = lane & 15, quad = lane >> 4;
  int b = blockIdx.z;
  int tM = blockIdx.y * 128 + (wv & 1) * 64;
  int tN = blockIdx.x * 128;
  int nloc = (wv >> 1) * 64;
  const u16* Ah = xnh + ((long)b*NPQ + tM + ml)*DIM;
  const u16* Al = xnl + ((long)b*NPQ + tM + ml)*DIM;
  f32x4 acc[4][4];
  f32x4 zer = {0.f,0.f,0.f,0.f};
#pragma unroll
  for (int i = 0; i < 4; i++)
#pragma unroll
    for (int j = 0; j < 4; j++) acc[i][j] = zer;

  int srow = t >> 4, scg = t & 15;
  for (int half = 0; half < 2; half++){
    int k0 = half * 128;
    if (half) __syncthreads();
#pragma unroll
    for (int p = 0; p < 8; p++){
      int r = p*16 + srow;
      long g = ((long)b*MNP + tN + r)*DIM + k0 + scg*8;
      *(uint4*)(&Bh[r*BST + scg*8]) = *(const uint4*)(mnh + g);
      *(uint4*)(&Bl[r*BST + scg*8]) = *(const uint4*)(mnl + g);
    }
    bf16x8 ca[4], ca2[4], na[4], na2[4];
#pragma unroll
    for (int i = 0; i < 4; i++){
      ca[i]  = *(const bf16x8*)(Ah + (long)i*16*DIM + k0 + quad*8);
      ca2[i] = *(const bf16x8*)(Al + (long)i*16*DIM + k0 + quad*8);
    }
    __syncthreads();
#pragma unroll
    for (int kk = 0; kk < 128; kk += 32){
      if (kk < 96){
#pragma unroll
        for (int i = 0; i < 4; i++){
          na[i]  = *(const bf16x8*)(Ah + (long)i*16*DIM + k0 + kk + 32 + quad*8);
          na2[i] = *(const bf16x8*)(Al + (long)i*16*DIM + k0 + kk + 32 + quad*8);
        }
      }
      bf16x8 bh[4], bl[4];
#pragma unroll
      for (int j = 0; j < 4; j++){
        int nr = nloc + j*16 + ml;
        bh[j] = *(const bf16x8*)(&Bh[nr*BST + kk + quad*8]);
        bl[j] = *(const bf16x8*)(&Bl[nr*BST + kk + quad*8]);
      }
#pragma unroll
      for (int i = 0; i < 4; i++)
#pragma unroll
        for (int j = 0; j < 4; j++){
          acc[i][j] = __builtin_amdgcn_mfma_f32_16x16x32_bf16(ca[i],  bh[j], acc[i][j], 0, 0, 0);
          acc[i][j] = __builtin_amdgcn_mfma_f32_16x16x32_bf16(ca[i],  bl[j], acc[i][j], 0, 0, 0);
          acc[i][j] = __builtin_amdgcn_mfma_f32_16x16x32_bf16(ca2[i], bh[j], acc[i][j], 0, 0, 0);
        }
#pragma unroll
      for (int i = 0; i < 4; i++){ ca[i] = na[i]; ca2[i] = na2[i]; }
    }
  }
  long zC = (long)b * NPQ * MNP;
#pragma unroll
  for (int i = 0; i < 4; i++)
#pragma unroll
    for (int r = 0; r < 4; r++){
      int row = tM + i*16 + quad*4 + r;
#pragma unroll
      for (int j = 0; j < 4; j++){
        int col = tN + nloc + j*16 + ml;
        sim[zC + (long)row*MNP + col] = acc[i][j][r];
      }
    }
}

// ---------------- projection GEMM ----------------
#define PBST 264
template<int KGROUPS, int OUT_BF16, int ACT>
__global__ __launch_bounds__(256)
void pgemm(const u16* __restrict__ A, const u16* __restrict__ A2, int selCol,
           const u16* __restrict__ B, const float* __restrict__ bias,
           void* __restrict__ Cv, int N){
  __shared__ __align__(16) u16 Bs[64*PBST];
  const int K = KGROUPS*256;
  int t = threadIdx.x, lane = t & 63, wv = t >> 6;
  int ml = lane & 15, quad = lane >> 4;
  int tM = blockIdx.x*64;
  int tN = blockIdx.y*64;
  const u16* Ab = (tN < selCol) ? A : A2;
  const u16* Arow = Ab + (long)(tM + wv*16 + ml)*K;
  f32x4 acc[4];
  f32x4 zer = {0.f,0.f,0.f,0.f};
#pragma unroll
  for (int nj = 0; nj < 4; nj++) acc[nj] = zer;
  int srow = t >> 5, scol = (t & 31)*8;
  for (int g = 0; g < KGROUPS; g++){
    if (g) __syncthreads();
#pragma unroll
    for (int p = 0; p < 8; p++){
      int r = p*8 + srow;
      *(uint4*)(&Bs[r*PBST + scol]) = *(const uint4*)(B + (long)(tN + r)*K + g*256 + scol);
    }
    bf16x8 a[8];
#pragma unroll
    for (int kk = 0; kk < 8; kk++)
      a[kk] = *(const bf16x8*)(Arow + g*256 + kk*32 + quad*8);
    __syncthreads();
#pragma unroll
    for (int kk = 0; kk < 8; kk++){
#pragma unroll
      for (int nj = 0; nj < 4; nj++){
        bf16x8 bv = *(const bf16x8*)(&Bs[(nj*16 + ml)*PBST + kk*32 + quad*8]);
        acc[nj] = __builtin_amdgcn_mfma_f32_16x16x32_bf16(a[kk], bv, acc[nj], 0, 0, 0);
      }
    }
  }
#pragma unroll
  for (int nj = 0; nj < 4; nj++){
    int col = tN + nj*16 + ml;
    float bv = bias[col];
#pragma unroll
    for (int r = 0; r < 4; r++){
      int row = tM + wv*16 + quad*4 + r;
      float v = acc[nj][r] + bv;
      if (ACT == 1) v = gelu_exact(v);
      long idx = (long)row * N + col;
      if (OUT_BF16) ((u16*)Cv)[idx] = f2bf(v);
      else ((float*)Cv)[idx] = v;
    }
  }
}

// ---------------- top-k: radix-select, 12/8/8/4-bit rounds ---------------
// R12 history: plain 8-bit radix ~38us (hot exponent bins -> ~64-way
// same-address LDS atomic serialization within each wave instr). R8
// per-wave copies: neutral (contention is intra-wave). R11 ballot
// aggregation: WORSE (80us; ~20 distinct digits -> serial VALU loop cost
// > atomic cost; conflicts 0 but VALUBusy 56%). R12 fix: widen round-0
// digit to 12 bits (sign + exp + 3 mantissa bits, 4096 bins) -> hot bins
// split 8x -> ~8-way conflicts, plain atomics kept. Rounds: 12/8/8/4.
// Scan: per-thread 16-bin sum -> wave suffix-scan -> cross-wave via
// wsum[4] -> in-thread high->low walk re-reading hist (NO aggregate
// crosses a barrier, per the R0/R3/R6 spill lesson; only scalars cross).
// Selection semantics identical: pref = exact key of 32nd largest,
// k_above = count strictly greater; emission tail unchanged.
template<int SHIFT, int NB, int FIRST>
__device__ __forceinline__
void radix_round(const u32* key, u32& pref, int& k_above,
                 int* hist, int* wsum, int* sel){
  constexpr int LOG  = (NB == 4096) ? 12 : (NB == 256) ? 8 : 4;
  constexpr int NBPT = (NB > 256) ? (NB / 256) : 1;   // bins per thread
  constexpr int OWN  = (NB < 256) ? NB : 256;          // owner threads
  constexpr u32 pmask = FIRST ? 0u : (u32)(0xFFFFFFFFull << (SHIFT + LOG));
  int t = threadIdx.x, lane = t & 63, wv = t >> 6;
  for (int z = t; z < NB; z += 256) hist[z] = 0;
  if (t < 4) wsum[t] = 0;
  __syncthreads();
#pragma unroll
  for (int i = 0; i < 16; i++){
    if (((key[i] ^ pref) & pmask) == 0)
      atomicAdd(&hist[(key[i] >> SHIFT) & (NB - 1)], 1);
  }
  __syncthreads();
  int local = 0, s = 0;
  if (t < OWN){
#pragma unroll
    for (int j = 0; j < NBPT; j++) local += hist[t*NBPT + j];
    s = local;
#pragma unroll
    for (int off = 1; off < 64; off <<= 1){
      int v = __shfl_down(s, off, 64);
      s += (lane + off < 64 && t + off < OWN) ? v : 0;
    }
    if (lane == 0) wsum[wv] = s;   // s at lane0 = this wave's total
  }
  __syncthreads();
  if (t < OWN){
    int cross = 0;
#pragma unroll
    for (int w = 1; w < 4; w++) if (w > wv) cross += wsum[w];
    int runs = (s - local) + cross;   // keys in bins owned by threads > t
    int ka = k_above;
#pragma unroll
    for (int j = NBPT - 1; j >= 0; j--){
      int hj = hist[t*NBPT + j];
      if (ka + runs < TOPK && ka + runs + hj >= TOPK){
        sel[0] = t*NBPT + j; sel[1] = ka + runs;
      }
      runs += hj;
    }
  }
  __syncthreads();
  pref |= ((u32)sel[0]) << SHIFT;
  k_above = sel[1];
}

__global__ __launch_bounds__(256, 4)
void topk_k(const float* __restrict__ sim, int* __restrict__ rns){
  __shared__ int hist[4096];
  __shared__ int sties[256];
  __shared__ int wsum[4];
  __shared__ int sel2[2];
  __shared__ int cnt2[2];   // scnt, stcnt
  int t = threadIdx.x;
  long r = blockIdx.x;
  const uint4* row4 = (const uint4*)(sim + r*4096);
  u32 key[16];
#pragma unroll
  for (int j = 0; j < 4; j++){
    uint4 v = row4[j*256 + t];
    key[j*4+0] = keytr(v.x);
    key[j*4+1] = keytr(v.y);
    key[j*4+2] = keytr(v.z);
    key[j*4+3] = keytr(v.w);
  }
#pragma unroll
  for (int i = 0; i < 16; i++) asm volatile("" : "+v"(key[i]));
  if (t == 0){ cnt2[0] = 0; cnt2[1] = 0; }
  u32 pref = 0;
  int k_above = 0;
  radix_round<20, 4096, 1>(key, pref, k_above, hist, wsum, sel2);
  radix_round<12,  256, 0>(key, pref, k_above, hist, wsum, sel2);
  radix_round< 4,  256, 0>(key, pref, k_above, hist, wsum, sel2);
  radix_round< 0,   16, 0>(key, pref, k_above, hist, wsum, sel2);
  int* out = rns + r*32;
#pragma unroll
  for (int i = 0; i < 16; i++){
    int gidx = (i >> 2)*1024 + t*4 + (i & 3);
    u32 kk = key[i];
    if (kk > pref){
      int p = atomicAdd(&cnt2[0], 1);
      out[p] = gidx;
    } else if (kk == pref){
      int p = atomicAdd(&cnt2[1], 1);
      if (p < 256) sties[p] = gidx;
    }
  }
  __syncthreads();
  if (t == 0){
    int n = cnt2[1]; if (n > 256) n = 256;
    int k_rem = TOPK - k_above;   // >= 1 by construction
    for (int s = 0; s < k_rem; s++){
      int mb = 0;
      for (int j = 1; j < n; j++) if (sties[j] < sties[mb]) mb = j;
      out[k_above + s] = sties[mb];
      sties[mb] = 0x7FFFFFFF;
    }
  }
}

// ---------------- sparse gathered cross-attention ----------------
// khvh layout: [32768][512], K at col 0..255, V at col 256..511
#define CAS 272
__global__ __launch_bounds__(256)
void cross_attn(const u16* __restrict__ qh, const u16* __restrict__ khvh,
                const int* __restrict__ rns, float* __restrict__ crossO){
  __shared__ __align__(16) u16 Kg[32*CAS];
  __shared__ __align__(16) u16 Vg[32*CAS];
  __shared__ float qv[256];
  __shared__ int idxs[32];
  __shared__ float L[256];
  __shared__ float pm[8], ps[8];
  int r = blockIdx.x, t = threadIdx.x;
  int b = r >> 9;
  if (t < 32) idxs[t] = rns[(long)r*32 + t];
  qv[t] = bf2f(qh[(long)r*DIM + t]);
  __syncthreads();
  for (int i = t; i < 32*64; i += 256){
    int k = i >> 6, c = (i & 63) * 4;
    long src = ((long)b*MNP + idxs[k])*512 + c;
    *(ushort4*)(&Kg[k*CAS + c]) = *(const ushort4*)(khvh + src);
    *(ushort4*)(&Vg[k*CAS + c]) = *(const ushort4*)(khvh + src + 256);
  }
  __syncthreads();
  {
    int h = t >> 5, k = t & 31;
    float acc = 0.f;
#pragma unroll
    for (int d = 0; d < 32; d++) acc += qv[h*HD + d] * bf2f(Kg[k*CAS + h*HD + d]);
    L[t] = acc * SCALE;
  }
  __syncthreads();
  if (t < 8){
    float m = L[t*32];
    for (int k = 1; k < 32; k++) m = fmaxf(m, L[t*32 + k]);
    float s = 0.f;
    for (int k = 0; k < 32; k++) s += expf(L[t*32 + k] - m);
    pm[t] = m; ps[t] = s;
  }
  __syncthreads();
  {
    int h = t >> 5, dd = t & 31;
    float m = pm[h], inv = 1.0f/ps[h], acc = 0.f;
#pragma unroll
    for (int k = 0; k < 32; k++) acc += expf(L[h*32 + k] - m) * bf2f(Vg[k*CAS + h*HD + dd]);
    crossO[(long)r*DIM + t] = acc * inv;
  }
}

// ---------------- fused layernorms ----------------
template<int MODE>
__global__ __launch_bounds__(256)
void ln_k(const float* __restrict__ xa, const float* __restrict__ xb,
          const float* __restrict__ qpos,
          const float* __restrict__ w, const float* __restrict__ bsh,
          float* __restrict__ yf, u16* __restrict__ yb, u16* __restrict__ qkb){
  __shared__ float sc[8];
  int r = blockIdx.x, t = threadIdx.x;
  int b = r >> 9, n = r & 511;
  long bidx = (long)r*DIM + t;
  long nidx = ((long)n*BSZ + b)*DIM + t;
  float x = (MODE == 1 ? xa[nidx] : xa[bidx]) + xb[bidx];
  float s  = wredsum(x);
  float s2 = wredsum(x*x);
  int wv = t >> 6;
  if ((t & 63) == 0){ sc[wv] = s; sc[4 + wv] = s2; }
  __syncthreads();
  float S  = sc[0]+sc[1]+sc[2]+sc[3];
  float S2 = sc[4]+sc[5]+sc[6]+sc[7];
  float mu  = S * (1.f/256.f);
  float var = S2 * (1.f/256.f) - mu*mu;
  float y = (x - mu) * (1.0f / sqrtf(var + 1e-5f)) * w[t] + bsh[t];
  if (MODE == 3){
    yf[nidx] = y;
  } else {
    yf[bidx] = y;
    yb[bidx] = f2bf(y);
    if (MODE == 1) qkb[bidx] = f2bf(y + qpos[nidx]);
  }
}

// ---------------- fused dense self-attention (MFMA) ----------------
// qkv layout: [4096][768], q at 0, k at 256, v at 512.
#define KST 40
#define PST 264
__global__ __launch_bounds__(256)
void self_attn(const u16* __restrict__ qkv, u16* __restrict__ sa_pre){
  __shared__ __align__(16) u16 KS[512*KST];
  __shared__ __align__(16) u16 QS[32*KST];
  __shared__ float mbuf[128];
  __shared__ float sbuf[128];
  u16* P  = KS;
  u16* Vt = KS + 32*PST;

  int qt = blockIdx.x, h = blockIdx.y, b = blockIdx.z;
  int t = threadIdx.x, lane = t & 63, wv = t >> 6;
  int ml = lane & 15, quad = lane >> 4;
  int n0 = qt * 32;

  {
    int q = t >> 3, d4 = (t & 7) * 4;
    const u16* src = qkv + ((long)b*NPQ + n0 + q)*768 + h*HD + d4;
    *(ushort2*)(QS + q*KST + d4)     = *(const ushort2*)(src);
    *(ushort2*)(QS + q*KST + d4 + 2) = *(const ushort2*)(src + 2);
  }
  for (int i = t; i < 512*8; i += 256){
    int j = i >> 3, d4 = (i & 7) * 4;
    const u16* src = qkv + ((long)b*NPQ + j)*768 + 256 + h*HD + d4;
    *(ushort2*)(KS + j*KST + d4)     = *(const ushort2*)(src);
    *(ushort2*)(KS + j*KST + d4 + 2) = *(const ushort2*)(src + 2);
  }
  __syncthreads();

  f32x4 acc[2][8];
  {
    bf16x8 aq[2];
#pragma unroll
    for (int mi = 0; mi < 2; mi++)
      aq[mi] = *(const bf16x8*)(QS + (mi*16 + ml)*KST + quad*8);
#pragma unroll
    for (int nj = 0; nj < 8; nj++){
      bf16x8 bk = *(const bf16x8*)(KS + (wv*128 + nj*16 + ml)*KST + quad*8);
      f32x4 z = {0.f,0.f,0.f,0.f};
#pragma unroll
      for (int mi = 0; mi < 2; mi++)
        acc[mi][nj] = __builtin_amdgcn_mfma_f32_16x16x32_bf16(aq[mi], bk, z, 0, 0, 0);
    }
  }
  float lmax[2][4];
#pragma unroll
  for (int mi = 0; mi < 2; mi++)
#pragma unroll
    for (int r = 0; r < 4; r++) lmax[mi][r] = -3.4e38f;
#pragma unroll
  for (int mi = 0; mi < 2; mi++)
#pragma unroll
    for (int nj = 0; nj < 8; nj++)
#pragma unroll
      for (int r = 0; r < 4; r++){
        float v = acc[mi][nj][r] * SCALE;
        acc[mi][nj][r] = v;
        lmax[mi][r] = fmaxf(lmax[mi][r], v);
      }
#pragma unroll
  for (int m = 1; m < 16; m <<= 1)
#pragma unroll
    for (int mi = 0; mi < 2; mi++)
#pragma unroll
      for (int r = 0; r < 4; r++)
        lmax[mi][r] = fmaxf(lmax[mi][r], __shfl_xor(lmax[mi][r], m, 64));
  if (ml == 0){
#pragma unroll
    for (int mi = 0; mi < 2; mi++)
#pragma unroll
      for (int r = 0; r < 4; r++)
        mbuf[(mi*16 + quad*4 + r)*4 + wv] = lmax[mi][r];
  }
  __syncthreads();
  float inv_[2][4];
  float lsum[2][4];
#pragma unroll
  for (int mi = 0; mi < 2; mi++)
#pragma unroll
    for (int r = 0; r < 4; r++){
      int row = mi*16 + quad*4 + r;
      float m0 = fmaxf(fmaxf(mbuf[row*4+0], mbuf[row*4+1]),
                       fmaxf(mbuf[row*4+2], mbuf[row*4+3]));
      float s = 0.f;
#pragma unroll
      for (int nj = 0; nj < 8; nj++){
        float e = __expf(acc[mi][nj][r] - m0);
        acc[mi][nj][r] = e;
        s += e;
      }
      lsum[mi][r] = s;
    }
#pragma unroll
  for (int m = 1; m < 16; m <<= 1)
#pragma unroll
    for (int mi = 0; mi < 2; mi++)
#pragma unroll
      for (int r = 0; r < 4; r++)
        lsum[mi][r] += __shfl_xor(lsum[mi][r], m, 64);
  if (ml == 0){
#pragma unroll
    for (int mi = 0; mi < 2; mi++)
#pragma unroll
      for (int r = 0; r < 4; r++)
        sbuf[(mi*16 + quad*4 + r)*4 + wv] = lsum[mi][r];
  }
  __syncthreads();
#pragma unroll
  for (int mi = 0; mi < 2; mi++)
#pragma unroll
    for (int r = 0; r < 4; r++){
      int row = mi*16 + quad*4 + r;
      inv_[mi][r] = 1.0f / (sbuf[row*4+0]+sbuf[row*4+1]+sbuf[row*4+2]+sbuf[row*4+3]);
    }

  int mi2 = wv >> 1, ni = wv & 1;
  f32x4 acc2 = {0.f,0.f,0.f,0.f};
  for (int half = 0; half < 2; half++){
    __syncthreads();
    if ((wv >> 1) == half){
      int cbase = (wv & 1) * 128;
#pragma unroll
      for (int mi = 0; mi < 2; mi++)
#pragma unroll
        for (int nj = 0; nj < 8; nj++)
#pragma unroll
          for (int r = 0; r < 4; r++)
            P[(mi*16 + quad*4 + r)*PST + cbase + nj*16 + ml] = f2bf(acc[mi][nj][r]);
    }
    for (int i = t; i < 2048; i += 256){
      int j = i >> 3, d4 = (i & 7) * 4;
      const u16* src = qkv + ((long)b*NPQ + half*256 + j)*768 + 512 + h*HD + d4;
      u16 v0 = src[0], v1 = src[1], v2e = src[2], v3 = src[3];
      Vt[(d4+0)*PST + j] = v0;
      Vt[(d4+1)*PST + j] = v1;
      Vt[(d4+2)*PST + j] = v2e;
      Vt[(d4+3)*PST + j] = v3;
    }
    __syncthreads();
#pragma unroll
    for (int k0 = 0; k0 < 256; k0 += 32){
      bf16x8 ap = *(const bf16x8*)(P  + (mi2*16 + ml)*PST + k0 + quad*8);
      bf16x8 bv = *(const bf16x8*)(Vt + (ni*16  + ml)*PST + k0 + quad*8);
      acc2 = __builtin_amdgcn_mfma_f32_16x16x32_bf16(ap, bv, acc2, 0, 0, 0);
    }
  }
#pragma unroll
  for (int r = 0; r < 4; r++){
    int row = mi2*16 + quad*4 + r;
    sa_pre[((long)b*NPQ + n0 + row)*DIM + h*HD + ni*16 + ml] =
        f2bf(acc2[r] * inv_[mi2][r]);
  }
}

// =====================================================================
extern "C" void kernel_launch(void* const* d_in, const int* in_sizes, int n_in,
                              void* d_out, int out_size, void* d_ws, size_t ws_size,
                              hipStream_t stream){
  (void)in_sizes; (void)n_in; (void)out_size; (void)ws_size;
  const float* tgt  = (const float*)d_in[0];
  const float* mem  = (const float*)d_in[1];
  const float* qpos = (const float*)d_in[2];
  const float* kpos = (const float*)d_in[3];
  const float* cw1  = (const float*)d_in[4];  const float* cb1 = (const float*)d_in[5];
  const float* cw2  = (const float*)d_in[6];  const float* cb2 = (const float*)d_in[7];
  const float* cw3  = (const float*)d_in[8];  const float* cb3 = (const float*)d_in[9];
  const float* saw  = (const float*)d_in[10]; const float* sab = (const float*)d_in[11];
  const float* sow  = (const float*)d_in[12]; const float* sob = (const float*)d_in[13];
  const float* ln1w = (const float*)d_in[14]; const float* ln1b = (const float*)d_in[15];
  const float* ln2w = (const float*)d_in[16]; const float* ln2b = (const float*)d_in[17];
  const float* ln3w = (const float*)d_in[18]; const float* ln3b = (const float*)d_in[19];
  const float* f1w  = (const float*)d_in[20]; const float* f1bs = (const float*)d_in[21];
  const float* f2w  = (const float*)d_in[22]; const float* f2bs = (const float*)d_in[23];

  char* base = (char*)d_ws;
  size_t off = 0;
  auto alloc = [&](size_t bytes) -> char* {
    char* p = base + off;
    off += (bytes + 255) & ~(size_t)255;
    return p;
  };
  u16* cw1b = (u16*)alloc(65536u*2);
  u16* cw2b = (u16*)alloc(65536u*2);
  u16* cw3b = (u16*)alloc(65536u*2);   (void)cw3b;
  u16* sawb = (u16*)alloc(196608u*2);
  u16* sowb = (u16*)alloc(65536u*2);
  u16* f1wb = (u16*)alloc(524288u*2);
  u16* f2wb = (u16*)alloc(524288u*2);
  int* rns  = (int*)alloc(4096u*32*4);
  float* cbKV = (float*)alloc(512*4);
  size_t offB = off;
  u16* xnh = (u16*)alloc((size_t)4096*256*2);
  u16* xnl = (u16*)alloc((size_t)4096*256*2);
  u16* mnh = (u16*)alloc((size_t)32768*256*2);
  u16* mnl = (u16*)alloc((size_t)32768*256*2);
  u16* qc  = (u16*)alloc((size_t)4096*256*2);
  u16* kc  = (u16*)alloc((size_t)32768*256*2);
  u16* vc  = (u16*)alloc((size_t)32768*256*2);
  float* sim = (float*)alloc((size_t)8*512*4096*4);

  char* regC = (char*)sim;
  u16* qh   = (u16*)regC;                      // [4096][256]  2 MB
  u16* khvh = (u16*)(regC + 2097152);          // [32768][512] 32 MB
  char* regB = base + offB;
  size_t ob = 0;
  auto allocB = [&](size_t bytes) -> char* {
    char* p = regB + ob;
    ob += (bytes + 255) & ~(size_t)255;
    return p;
  };
  float* cross = (float*)allocB((size_t)4096*256*4);
  float* t1    = (float*)allocB((size_t)4096*256*4);
  u16*   t1b   = (u16*)allocB((size_t)4096*256*2);
  u16*   qkb   = (u16*)allocB((size_t)4096*256*2);
  u16*   qkv   = (u16*)allocB((size_t)4096*768*2);
  u16*   sa_pre= (u16*)allocB((size_t)4096*256*2);
  float* sa    = (float*)allocB((size_t)4096*256*4);
  float* t2    = (float*)allocB((size_t)4096*256*4);
  u16*   t2b   = (u16*)allocB((size_t)4096*256*2);
  u16*   h1    = (u16*)allocB((size_t)4096*2048*2);
  float* ff    = (float*)allocB((size_t)4096*256*4);

  const int BIG = 1 << 30;
  dim3 blk(256);
  fused_prep<<<dim3(FP_TOT_B), blk, 0, stream>>>(
      mem, kpos, mnh, mnl, kc, vc,
      tgt, qpos, xnh, xnl, qc, cb2, cb3, cbKV,
      cw1, cw2, cw3, saw, sow, f1w, f2w, cw1b);
  sim_gemm<<<dim3(32,4,8), blk, 0, stream>>>(xnh, xnl, mnh, mnl, sim);
  topk_k<<<dim3(4096), blk, 0, stream>>>(sim, rns);
  pgemm<1,1,0><<<dim3(64,4), blk, 0, stream>>>(qc, qc, BIG, cw1b, cb1, qh, 256);
  pgemm<1,1,0><<<dim3(512,8), blk, 0, stream>>>(kc, vc, 256, cw2b, cbKV, khvh, 512);
  cross_attn<<<dim3(4096), blk, 0, stream>>>(qh, khvh, rns, cross);
  ln_k<1><<<dim3(4096), blk, 0, stream>>>(tgt, cross, qpos, ln1w, ln1b, t1, t1b, qkb);
  pgemm<1,1,0><<<dim3(64,12), blk, 0, stream>>>(qkb, t1b, 512, sawb, sab, qkv, 768);
  self_attn<<<dim3(16,8,8), blk, 0, stream>>>(qkv, sa_pre);
  pgemm<1,0,0><<<dim3(64,4), blk, 0, stream>>>(sa_pre, sa_pre, BIG, sowb, sob, sa, 256);
  ln_k<2><<<dim3(4096), blk, 0, stream>>>(t1, sa, nullptr, ln2w, ln2b, t2, t2b, nullptr);
  pgemm<1,1,1><<<dim3(64,32), blk, 0, stream>>>(t2b, t2b, BIG, f1wb, f1bs, h1, 2048);
  pgemm<8,0,0><<<dim3(64,4), blk, 0, stream>>>(h1, h1, BIG, f2wb, f2bs, ff, 256);
  ln_k<3><<<dim3(4096), blk, 0, stream>>>(t2, ff, nullptr, ln3w, ln3b, (float*)d_out, nullptr, nullptr);
}

// Round 13
// 409.849 us; speedup vs baseline: 1.1196x; 1.0476x over previous
//
#include <hip/hip_runtime.h>
#include <math.h>

typedef unsigned short u16;
typedef unsigned int u32;
typedef __bf16 bf16x8 __attribute__((ext_vector_type(8)));
typedef float f32x4 __attribute__((ext_vector_type(4)));

#define NPQ 512
#define MNP 4096
#define BSZ 8
#define DIM 256
#define NH 8
#define HD 32
#define TOPK 32
#define FFD 2048
#define SCALE 0.17677669529663687f  // 1/sqrt(32)

__device__ __forceinline__ u16 f2bf(float f){
  u32 u = __builtin_bit_cast(u32, f);
  u = (u + 0x7FFFu + ((u >> 16) & 1u)) >> 16;
  return (u16)u;
}
__device__ __forceinline__ float bf2f(u16 h){
  u32 u = ((u32)h) << 16;
  return __builtin_bit_cast(float, u);
}
__device__ __forceinline__ float wredsum(float v){
#pragma unroll
  for (int m = 32; m; m >>= 1) v += __shfl_xor(v, m, 64);
  return v;
}
__device__ __forceinline__ float gelu_exact(float x){
  return 0.5f * x * (1.0f + erff(x * 0.70710678118654752f));
}
__device__ __forceinline__ u32 keytr(u32 u){
  return u ^ (((u32)((int)u >> 31)) | 0x80000000u);
}

// ---------------- fused prep: vectorized wave-per-row --------------------
// R13: R12 counters showed fused_prep at 2.2 TB/s (28% peak), VALUBusy 40%
// -- scalar 4B loads + 2B stores + needless block-wide LDS reduction
// (Common-mistake #2 / Guideline 13). Now one WAVE per row: lane l owns
// elements 4l..4l+3 -> float4 loads (16B/lane), ushort4 stores (8B/lane),
// row sum via per-lane 4-square sum + wredsum (no LDS, no barrier).
// cvt_all likewise float4->ushort4 (segment bounds all multiples of 4).
// Per-element arithmetic unchanged (x / sqrtf(tot), same f2bf).
#define FP_MEM_B 8192
#define FP_TGT_B (8192 + 1024)
#define FP_TOT_B (8192 + 1024 + 1472)
__global__ __launch_bounds__(256)
void fused_prep(const float* __restrict__ mem, const float* __restrict__ kpos,
                u16* __restrict__ mnh, u16* __restrict__ mnl,
                u16* __restrict__ kc, u16* __restrict__ vc,
                const float* __restrict__ tgt, const float* __restrict__ qpos,
                u16* __restrict__ xnh, u16* __restrict__ xnl, u16* __restrict__ qc,
                const float* __restrict__ cb2, const float* __restrict__ cb3,
                float* __restrict__ cbKV,
                const float* __restrict__ s0, const float* __restrict__ s1,
                const float* __restrict__ s2, const float* __restrict__ s3,
                const float* __restrict__ s4, const float* __restrict__ s5,
                const float* __restrict__ s6, u16* __restrict__ wdst){
  int gb = blockIdx.x, t = threadIdx.x, wv = t >> 6, lane = t & 63;
  if (gb < FP_MEM_B){
    int r = gb*4 + wv;
    int b = r >> 12, mp = r & 4095;
    long src = ((long)mp*BSZ + b)*DIM + lane*4;
    float4 x  = *(const float4*)(mem + src);
    float4 kp = *(const float4*)(kpos + src);
    float s = wredsum(x.x*x.x + x.y*x.y + x.z*x.z + x.w*x.w);
    float sq = sqrtf(s);
    float n0 = x.x/sq, n1 = x.y/sq, n2 = x.z/sq, n3 = x.w/sq;
    ushort4 h, lo, kv, vv;
    h.x = f2bf(n0); h.y = f2bf(n1); h.z = f2bf(n2); h.w = f2bf(n3);
    lo.x = f2bf(n0 - bf2f(h.x)); lo.y = f2bf(n1 - bf2f(h.y));
    lo.z = f2bf(n2 - bf2f(h.z)); lo.w = f2bf(n3 - bf2f(h.w));
    kv.x = f2bf(x.x + kp.x); kv.y = f2bf(x.y + kp.y);
    kv.z = f2bf(x.z + kp.z); kv.w = f2bf(x.w + kp.w);
    vv.x = f2bf(x.x); vv.y = f2bf(x.y); vv.z = f2bf(x.z); vv.w = f2bf(x.w);
    long dst = (long)r*DIM + lane*4;
    *(ushort4*)(mnh + dst) = h;
    *(ushort4*)(mnl + dst) = lo;
    *(ushort4*)(kc  + dst) = kv;
    *(ushort4*)(vc  + dst) = vv;
  } else if (gb < FP_TGT_B){
    int r = (gb - FP_MEM_B)*4 + wv;
    if (r == 0){
      *(float4*)(cbKV + lane*4)       = *(const float4*)(cb2 + lane*4);
      *(float4*)(cbKV + 256 + lane*4) = *(const float4*)(cb3 + lane*4);
    }
    int b = r >> 9, n = r & 511;
    long src = ((long)n*BSZ + b)*DIM + lane*4;
    float4 x  = *(const float4*)(tgt + src);
    float4 qp = *(const float4*)(qpos + src);
    float s = wredsum(x.x*x.x + x.y*x.y + x.z*x.z + x.w*x.w);
    float sq = sqrtf(s);
    float n0 = x.x/sq, n1 = x.y/sq, n2 = x.z/sq, n3 = x.w/sq;
    ushort4 h, lo, qv;
    h.x = f2bf(n0); h.y = f2bf(n1); h.z = f2bf(n2); h.w = f2bf(n3);
    lo.x = f2bf(n0 - bf2f(h.x)); lo.y = f2bf(n1 - bf2f(h.y));
    lo.z = f2bf(n2 - bf2f(h.z)); lo.w = f2bf(n3 - bf2f(h.w));
    qv.x = f2bf(x.x + qp.x); qv.y = f2bf(x.y + qp.y);
    qv.z = f2bf(x.z + qp.z); qv.w = f2bf(x.w + qp.w);
    long dst = (long)r*DIM + lane*4;
    *(ushort4*)(xnh + dst) = h;
    *(ushort4*)(xnl + dst) = lo;
    *(ushort4*)(qc  + dst) = qv;
  } else {
    int i = (((gb - FP_TGT_B)*256) + t) * 4;
    if (i >= 1507328) return;
    const float* s; int base;
    if      (i <  65536){ s = s0; base = 0; }
    else if (i < 131072){ s = s1; base = 65536; }
    else if (i < 196608){ s = s2; base = 131072; }
    else if (i < 393216){ s = s3; base = 196608; }
    else if (i < 458752){ s = s4; base = 393216; }
    else if (i < 983040){ s = s5; base = 458752; }
    else                { s = s6; base = 983040; }
    float4 x = *(const float4*)(s + (i - base));
    ushort4 o;
    o.x = f2bf(x.x); o.y = f2bf(x.y); o.z = f2bf(x.z); o.w = f2bf(x.w);
    *(ushort4*)(wdst + i) = o;
  }
}

// ---------------- sim GEMM (split bf16, LDS-staged B) ----------------
// R7: R2 structure (BK=128, BST=136, (256,2), in-wave A prefetch) -- the
// proven-fastest clean version (~50us, VGPR 116, no spill). Do NOT retry:
// (256,4)/BK=64 (acc spill), (256,3)/BK=64 (neutral), T14 reg-stage
// (staging spill). Compiler lesson: aggregates live across __syncthreads
// at 256 threads get spilled.
#define BST 136
__global__ __launch_bounds__(256, 2)
void sim_gemm(const u16* __restrict__ xnh, const u16* __restrict__ xnl,
              const u16* __restrict__ mnh, const u16* __restrict__ mnl,
              float* __restrict__ sim){
  __shared__ __align__(16) u16 Bh[128*BST];
  __shared__ __align__(16) u16 Bl[128*BST];
  int t = threadIdx.x, lane = t & 63, wv = t >> 6;
  int ml = lane & 15, quad = lane >> 4;
  int b = blockIdx.z;
  int tM = blockIdx.y * 128 + (wv & 1) * 64;
  int tN = blockIdx.x * 128;
  int nloc = (wv >> 1) * 64;
  const u16* Ah = xnh + ((long)b*NPQ + tM + ml)*DIM;
  const u16* Al = xnl + ((long)b*NPQ + tM + ml)*DIM;
  f32x4 acc[4][4];
  f32x4 zer = {0.f,0.f,0.f,0.f};
#pragma unroll
  for (int i = 0; i < 4; i++)
#pragma unroll
    for (int j = 0; j < 4; j++) acc[i][j] = zer;

  int srow = t >> 4, scg = t & 15;
  for (int half = 0; half < 2; half++){
    int k0 = half * 128;
    if (half) __syncthreads();
#pragma unroll
    for (int p = 0; p < 8; p++){
      int r = p*16 + srow;
      long g = ((long)b*MNP + tN + r)*DIM + k0 + scg*8;
      *(uint4*)(&Bh[r*BST + scg*8]) = *(const uint4*)(mnh + g);
      *(uint4*)(&Bl[r*BST + scg*8]) = *(const uint4*)(mnl + g);
    }
    bf16x8 ca[4], ca2[4], na[4], na2[4];
#pragma unroll
    for (int i = 0; i < 4; i++){
      ca[i]  = *(const bf16x8*)(Ah + (long)i*16*DIM + k0 + quad*8);
      ca2[i] = *(const bf16x8*)(Al + (long)i*16*DIM + k0 + quad*8);
    }
    __syncthreads();
#pragma unroll
    for (int kk = 0; kk < 128; kk += 32){
      if (kk < 96){
#pragma unroll
        for (int i = 0; i < 4; i++){
          na[i]  = *(const bf16x8*)(Ah + (long)i*16*DIM + k0 + kk + 32 + quad*8);
          na2[i] = *(const bf16x8*)(Al + (long)i*16*DIM + k0 + kk + 32 + quad*8);
        }
      }
      bf16x8 bh[4], bl[4];
#pragma unroll
      for (int j = 0; j < 4; j++){
        int nr = nloc + j*16 + ml;
        bh[j] = *(const bf16x8*)(&Bh[nr*BST + kk + quad*8]);
        bl[j] = *(const bf16x8*)(&Bl[nr*BST + kk + quad*8]);
      }
#pragma unroll
      for (int i = 0; i < 4; i++)
#pragma unroll
        for (int j = 0; j < 4; j++){
          acc[i][j] = __builtin_amdgcn_mfma_f32_16x16x32_bf16(ca[i],  bh[j], acc[i][j], 0, 0, 0);
          acc[i][j] = __builtin_amdgcn_mfma_f32_16x16x32_bf16(ca[i],  bl[j], acc[i][j], 0, 0, 0);
          acc[i][j] = __builtin_amdgcn_mfma_f32_16x16x32_bf16(ca2[i], bh[j], acc[i][j], 0, 0, 0);
        }
#pragma unroll
      for (int i = 0; i < 4; i++){ ca[i] = na[i]; ca2[i] = na2[i]; }
    }
  }
  long zC = (long)b * NPQ * MNP;
#pragma unroll
  for (int i = 0; i < 4; i++)
#pragma unroll
    for (int r = 0; r < 4; r++){
      int row = tM + i*16 + quad*4 + r;
#pragma unroll
      for (int j = 0; j < 4; j++){
        int col = tN + nloc + j*16 + ml;
        sim[zC + (long)row*MNP + col] = acc[i][j][r];
      }
    }
}

// ---------------- projection GEMM ----------------
#define PBST 264
template<int KGROUPS, int OUT_BF16, int ACT>
__global__ __launch_bounds__(256)
void pgemm(const u16* __restrict__ A, const u16* __restrict__ A2, int selCol,
           const u16* __restrict__ B, const float* __restrict__ bias,
           void* __restrict__ Cv, int N){
  __shared__ __align__(16) u16 Bs[64*PBST];
  const int K = KGROUPS*256;
  int t = threadIdx.x, lane = t & 63, wv = t >> 6;
  int ml = lane & 15, quad = lane >> 4;
  int tM = blockIdx.x*64;
  int tN = blockIdx.y*64;
  const u16* Ab = (tN < selCol) ? A : A2;
  const u16* Arow = Ab + (long)(tM + wv*16 + ml)*K;
  f32x4 acc[4];
  f32x4 zer = {0.f,0.f,0.f,0.f};
#pragma unroll
  for (int nj = 0; nj < 4; nj++) acc[nj] = zer;
  int srow = t >> 5, scol = (t & 31)*8;
  for (int g = 0; g < KGROUPS; g++){
    if (g) __syncthreads();
#pragma unroll
    for (int p = 0; p < 8; p++){
      int r = p*8 + srow;
      *(uint4*)(&Bs[r*PBST + scol]) = *(const uint4*)(B + (long)(tN + r)*K + g*256 + scol);
    }
    bf16x8 a[8];
#pragma unroll
    for (int kk = 0; kk < 8; kk++)
      a[kk] = *(const bf16x8*)(Arow + g*256 + kk*32 + quad*8);
    __syncthreads();
#pragma unroll
    for (int kk = 0; kk < 8; kk++){
#pragma unroll
      for (int nj = 0; nj < 4; nj++){
        bf16x8 bv = *(const bf16x8*)(&Bs[(nj*16 + ml)*PBST + kk*32 + quad*8]);
        acc[nj] = __builtin_amdgcn_mfma_f32_16x16x32_bf16(a[kk], bv, acc[nj], 0, 0, 0);
      }
    }
  }
#pragma unroll
  for (int nj = 0; nj < 4; nj++){
    int col = tN + nj*16 + ml;
    float bv = bias[col];
#pragma unroll
    for (int r = 0; r < 4; r++){
      int row = tM + wv*16 + quad*4 + r;
      float v = acc[nj][r] + bv;
      if (ACT == 1) v = gelu_exact(v);
      long idx = (long)row * N + col;
      if (OUT_BF16) ((u16*)Cv)[idx] = f2bf(v);
      else ((float*)Cv)[idx] = v;
    }
  }
}

// ---------------- top-k: radix-select, 12/8/8/4-bit rounds ---------------
// R12: widened round-0 digit to 12 bits (4096 bins) -> hot exponent bins
// split 8x -> ~8-way LDS-atomic conflicts, plain atomics kept. PROVEN
// (R12: topk left the top-5; conflicts ~0 on leaders). History: 8-bit
// ~38us (64-way same-addr serialization); per-wave copies neutral
// (intra-wave); ballot aggregation 80us (VALU loop > atomic cost).
template<int SHIFT, int NB, int FIRST>
__device__ __forceinline__
void radix_round(const u32* key, u32& pref, int& k_above,
                 int* hist, int* wsum, int* sel){
  constexpr int LOG  = (NB == 4096) ? 12 : (NB == 256) ? 8 : 4;
  constexpr int NBPT = (NB > 256) ? (NB / 256) : 1;   // bins per thread
  constexpr int OWN  = (NB < 256) ? NB : 256;          // owner threads
  constexpr u32 pmask = FIRST ? 0u : (u32)(0xFFFFFFFFull << (SHIFT + LOG));
  int t = threadIdx.x, lane = t & 63, wv = t >> 6;
  for (int z = t; z < NB; z += 256) hist[z] = 0;
  if (t < 4) wsum[t] = 0;
  __syncthreads();
#pragma unroll
  for (int i = 0; i < 16; i++){
    if (((key[i] ^ pref) & pmask) == 0)
      atomicAdd(&hist[(key[i] >> SHIFT) & (NB - 1)], 1);
  }
  __syncthreads();
  int local = 0, s = 0;
  if (t < OWN){
#pragma unroll
    for (int j = 0; j < NBPT; j++) local += hist[t*NBPT + j];
    s = local;
#pragma unroll
    for (int off = 1; off < 64; off <<= 1){
      int v = __shfl_down(s, off, 64);
      s += (lane + off < 64 && t + off < OWN) ? v : 0;
    }
    if (lane == 0) wsum[wv] = s;   // s at lane0 = this wave's total
  }
  __syncthreads();
  if (t < OWN){
    int cross = 0;
#pragma unroll
    for (int w = 1; w < 4; w++) if (w > wv) cross += wsum[w];
    int runs = (s - local) + cross;   // keys in bins owned by threads > t
    int ka = k_above;
#pragma unroll
    for (int j = NBPT - 1; j >= 0; j--){
      int hj = hist[t*NBPT + j];
      if (ka + runs < TOPK && ka + runs + hj >= TOPK){
        sel[0] = t*NBPT + j; sel[1] = ka + runs;
      }
      runs += hj;
    }
  }
  __syncthreads();
  pref |= ((u32)sel[0]) << SHIFT;
  k_above = sel[1];
}

__global__ __launch_bounds__(256, 4)
void topk_k(const float* __restrict__ sim, int* __restrict__ rns){
  __shared__ int hist[4096];
  __shared__ int sties[256];
  __shared__ int wsum[4];
  __shared__ int sel2[2];
  __shared__ int cnt2[2];   // scnt, stcnt
  int t = threadIdx.x;
  long r = blockIdx.x;
  const uint4* row4 = (const uint4*)(sim + r*4096);
  u32 key[16];
#pragma unroll
  for (int j = 0; j < 4; j++){
    uint4 v = row4[j*256 + t];
    key[j*4+0] = keytr(v.x);
    key[j*4+1] = keytr(v.y);
    key[j*4+2] = keytr(v.z);
    key[j*4+3] = keytr(v.w);
  }
#pragma unroll
  for (int i = 0; i < 16; i++) asm volatile("" : "+v"(key[i]));
  if (t == 0){ cnt2[0] = 0; cnt2[1] = 0; }
  u32 pref = 0;
  int k_above = 0;
  radix_round<20, 4096, 1>(key, pref, k_above, hist, wsum, sel2);
  radix_round<12,  256, 0>(key, pref, k_above, hist, wsum, sel2);
  radix_round< 4,  256, 0>(key, pref, k_above, hist, wsum, sel2);
  radix_round< 0,   16, 0>(key, pref, k_above, hist, wsum, sel2);
  int* out = rns + r*32;
#pragma unroll
  for (int i = 0; i < 16; i++){
    int gidx = (i >> 2)*1024 + t*4 + (i & 3);
    u32 kk = key[i];
    if (kk > pref){
      int p = atomicAdd(&cnt2[0], 1);
      out[p] = gidx;
    } else if (kk == pref){
      int p = atomicAdd(&cnt2[1], 1);
      if (p < 256) sties[p] = gidx;
    }
  }
  __syncthreads();
  if (t == 0){
    int n = cnt2[1]; if (n > 256) n = 256;
    int k_rem = TOPK - k_above;   // >= 1 by construction
    for (int s = 0; s < k_rem; s++){
      int mb = 0;
      for (int j = 1; j < n; j++) if (sties[j] < sties[mb]) mb = j;
      out[k_above + s] = sties[mb];
      sties[mb] = 0x7FFFFFFF;
    }
  }
}

// ---------------- sparse gathered cross-attention ----------------
// khvh layout: [32768][512], K at col 0..255, V at col 256..511
#define CAS 272
__global__ __launch_bounds__(256)
void cross_attn(const u16* __restrict__ qh, const u16* __restrict__ khvh,
                const int* __restrict__ rns, float* __restrict__ crossO){
  __shared__ __align__(16) u16 Kg[32*CAS];
  __shared__ __align__(16) u16 Vg[32*CAS];
  __shared__ float qv[256];
  __shared__ int idxs[32];
  __shared__ float L[256];
  __shared__ float pm[8], ps[8];
  int r = blockIdx.x, t = threadIdx.x;
  int b = r >> 9;
  if (t < 32) idxs[t] = rns[(long)r*32 + t];
  qv[t] = bf2f(qh[(long)r*DIM + t]);
  __syncthreads();
  for (int i = t; i < 32*64; i += 256){
    int k = i >> 6, c = (i & 63) * 4;
    long src = ((long)b*MNP + idxs[k])*512 + c;
    *(ushort4*)(&Kg[k*CAS + c]) = *(const ushort4*)(khvh + src);
    *(ushort4*)(&Vg[k*CAS + c]) = *(const ushort4*)(khvh + src + 256);
  }
  __syncthreads();
  {
    int h = t >> 5, k = t & 31;
    float acc = 0.f;
#pragma unroll
    for (int d = 0; d < 32; d++) acc += qv[h*HD + d] * bf2f(Kg[k*CAS + h*HD + d]);
    L[t] = acc * SCALE;
  }
  __syncthreads();
  if (t < 8){
    float m = L[t*32];
    for (int k = 1; k < 32; k++) m = fmaxf(m, L[t*32 + k]);
    float s = 0.f;
    for (int k = 0; k < 32; k++) s += expf(L[t*32 + k] - m);
    pm[t] = m; ps[t] = s;
  }
  __syncthreads();
  {
    int h = t >> 5, dd = t & 31;
    float m = pm[h], inv = 1.0f/ps[h], acc = 0.f;
#pragma unroll
    for (int k = 0; k < 32; k++) acc += expf(L[h*32 + k] - m) * bf2f(Vg[k*CAS + h*HD + dd]);
    crossO[(long)r*DIM + t] = acc * inv;
  }
}

// ---------------- fused layernorms ----------------
template<int MODE>
__global__ __launch_bounds__(256)
void ln_k(const float* __restrict__ xa, const float* __restrict__ xb,
          const float* __restrict__ qpos,
          const float* __restrict__ w, const float* __restrict__ bsh,
          float* __restrict__ yf, u16* __restrict__ yb, u16* __restrict__ qkb){
  __shared__ float sc[8];
  int r = blockIdx.x, t = threadIdx.x;
  int b = r >> 9, n = r & 511;
  long bidx = (long)r*DIM + t;
  long nidx = ((long)n*BSZ + b)*DIM + t;
  float x = (MODE == 1 ? xa[nidx] : xa[bidx]) + xb[bidx];
  float s  = wredsum(x);
  float s2 = wredsum(x*x);
  int wv = t >> 6;
  if ((t & 63) == 0){ sc[wv] = s; sc[4 + wv] = s2; }
  __syncthreads();
  float S  = sc[0]+sc[1]+sc[2]+sc[3];
  float S2 = sc[4]+sc[5]+sc[6]+sc[7];
  float mu  = S * (1.f/256.f);
  float var = S2 * (1.f/256.f) - mu*mu;
  float y = (x - mu) * (1.0f / sqrtf(var + 1e-5f)) * w[t] + bsh[t];
  if (MODE == 3){
    yf[nidx] = y;
  } else {
    yf[bidx] = y;
    yb[bidx] = f2bf(y);
    if (MODE == 1) qkb[bidx] = f2bf(y + qpos[nidx]);
  }
}

// ---------------- fused dense self-attention (MFMA) ----------------
// qkv layout: [4096][768], q at 0, k at 256, v at 512.
#define KST 40
#define PST 264
__global__ __launch_bounds__(256)
void self_attn(const u16* __restrict__ qkv, u16* __restrict__ sa_pre){
  __shared__ __align__(16) u16 KS[512*KST];
  __shared__ __align__(16) u16 QS[32*KST];
  __shared__ float mbuf[128];
  __shared__ float sbuf[128];
  u16* P  = KS;
  u16* Vt = KS + 32*PST;

  int qt = blockIdx.x, h = blockIdx.y, b = blockIdx.z;
  int t = threadIdx.x, lane = t & 63, wv = t >> 6;
  int ml = lane & 15, quad = lane >> 4;
  int n0 = qt * 32;

  {
    int q = t >> 3, d4 = (t & 7) * 4;
    const u16* src = qkv + ((long)b*NPQ + n0 + q)*768 + h*HD + d4;
    *(ushort2*)(QS + q*KST + d4)     = *(const ushort2*)(src);
    *(ushort2*)(QS + q*KST + d4 + 2) = *(const ushort2*)(src + 2);
  }
  for (int i = t; i < 512*8; i += 256){
    int j = i >> 3, d4 = (i & 7) * 4;
    const u16* src = qkv + ((long)b*NPQ + j)*768 + 256 + h*HD + d4;
    *(ushort2*)(KS + j*KST + d4)     = *(const ushort2*)(src);
    *(ushort2*)(KS + j*KST + d4 + 2) = *(const ushort2*)(src + 2);
  }
  __syncthreads();

  f32x4 acc[2][8];
  {
    bf16x8 aq[2];
#pragma unroll
    for (int mi = 0; mi < 2; mi++)
      aq[mi] = *(const bf16x8*)(QS + (mi*16 + ml)*KST + quad*8);
#pragma unroll
    for (int nj = 0; nj < 8; nj++){
      bf16x8 bk = *(const bf16x8*)(KS + (wv*128 + nj*16 + ml)*KST + quad*8);
      f32x4 z = {0.f,0.f,0.f,0.f};
#pragma unroll
      for (int mi = 0; mi < 2; mi++)
        acc[mi][nj] = __builtin_amdgcn_mfma_f32_16x16x32_bf16(aq[mi], bk, z, 0, 0, 0);
    }
  }
  float lmax[2][4];
#pragma unroll
  for (int mi = 0; mi < 2; mi++)
#pragma unroll
    for (int r = 0; r < 4; r++) lmax[mi][r] = -3.4e38f;
#pragma unroll
  for (int mi = 0; mi < 2; mi++)
#pragma unroll
    for (int nj = 0; nj < 8; nj++)
#pragma unroll
      for (int r = 0; r < 4; r++){
        float v = acc[mi][nj][r] * SCALE;
        acc[mi][nj][r] = v;
        lmax[mi][r] = fmaxf(lmax[mi][r], v);
      }
#pragma unroll
  for (int m = 1; m < 16; m <<= 1)
#pragma unroll
    for (int mi = 0; mi < 2; mi++)
#pragma unroll
      for (int r = 0; r < 4; r++)
        lmax[mi][r] = fmaxf(lmax[mi][r], __shfl_xor(lmax[mi][r], m, 64));
  if (ml == 0){
#pragma unroll
    for (int mi = 0; mi < 2; mi++)
#pragma unroll
      for (int r = 0; r < 4; r++)
        mbuf[(mi*16 + quad*4 + r)*4 + wv] = lmax[mi][r];
  }
  __syncthreads();
  float inv_[2][4];
  float lsum[2][4];
#pragma unroll
  for (int mi = 0; mi < 2; mi++)
#pragma unroll
    for (int r = 0; r < 4; r++){
      int row = mi*16 + quad*4 + r;
      float m0 = fmaxf(fmaxf(mbuf[row*4+0], mbuf[row*4+1]),
                       fmaxf(mbuf[row*4+2], mbuf[row*4+3]));
      float s = 0.f;
#pragma unroll
      for (int nj = 0; nj < 8; nj++){
        float e = __expf(acc[mi][nj][r] - m0);
        acc[mi][nj][r] = e;
        s += e;
      }
      lsum[mi][r] = s;
    }
#pragma unroll
  for (int m = 1; m < 16; m <<= 1)
#pragma unroll
    for (int mi = 0; mi < 2; mi++)
#pragma unroll
      for (int r = 0; r < 4; r++)
        lsum[mi][r] += __shfl_xor(lsum[mi][r], m, 64);
  if (ml == 0){
#pragma unroll
    for (int mi = 0; mi < 2; mi++)
#pragma unroll
      for (int r = 0; r < 4; r++)
        sbuf[(mi*16 + quad*4 + r)*4 + wv] = lsum[mi][r];
  }
  __syncthreads();
#pragma unroll
  for (int mi = 0; mi < 2; mi++)
#pragma unroll
    for (int r = 0; r < 4; r++){
      int row = mi*16 + quad*4 + r;
      inv_[mi][r] = 1.0f / (sbuf[row*4+0]+sbuf[row*4+1]+sbuf[row*4+2]+sbuf[row*4+3]);
    }

  int mi2 = wv >> 1, ni = wv & 1;
  f32x4 acc2 = {0.f,0.f,0.f,0.f};
  for (int half = 0; half < 2; half++){
    __syncthreads();
    if ((wv >> 1) == half){
      int cbase = (wv & 1) * 128;
#pragma unroll
      for (int mi = 0; mi < 2; mi++)
#pragma unroll
        for (int nj = 0; nj < 8; nj++)
#pragma unroll
          for (int r = 0; r < 4; r++)
            P[(mi*16 + quad*4 + r)*PST + cbase + nj*16 + ml] = f2bf(acc[mi][nj][r]);
    }
    for (int i = t; i < 2048; i += 256){
      int j = i >> 3, d4 = (i & 7) * 4;
      const u16* src = qkv + ((long)b*NPQ + half*256 + j)*768 + 512 + h*HD + d4;
      u16 v0 = src[0], v1 = src[1], v2e = src[2], v3 = src[3];
      Vt[(d4+0)*PST + j] = v0;
      Vt[(d4+1)*PST + j] = v1;
      Vt[(d4+2)*PST + j] = v2e;
      Vt[(d4+3)*PST + j] = v3;
    }
    __syncthreads();
#pragma unroll
    for (int k0 = 0; k0 < 256; k0 += 32){
      bf16x8 ap = *(const bf16x8*)(P  + (mi2*16 + ml)*PST + k0 + quad*8);
      bf16x8 bv = *(const bf16x8*)(Vt + (ni*16  + ml)*PST + k0 + quad*8);
      acc2 = __builtin_amdgcn_mfma_f32_16x16x32_bf16(ap, bv, acc2, 0, 0, 0);
    }
  }
#pragma unroll
  for (int r = 0; r < 4; r++){
    int row = mi2*16 + quad*4 + r;
    sa_pre[((long)b*NPQ + n0 + row)*DIM + h*HD + ni*16 + ml] =
        f2bf(acc2[r] * inv_[mi2][r]);
  }
}

// =====================================================================
extern "C" void kernel_launch(void* const* d_in, const int* in_sizes, int n_in,
                              void* d_out, int out_size, void* d_ws, size_t ws_size,
                              hipStream_t stream){
  (void)in_sizes; (void)n_in; (void)out_size; (void)ws_size;
  const float* tgt  = (const float*)d_in[0];
  const float* mem  = (const float*)d_in[1];
  const float* qpos = (const float*)d_in[2];
  const float* kpos = (const float*)d_in[3];
  const float* cw1  = (const float*)d_in[4];  const float* cb1 = (const float*)d_in[5];
  const float* cw2  = (const float*)d_in[6];  const float* cb2 = (const float*)d_in[7];
  const float* cw3  = (const float*)d_in[8];  const float* cb3 = (const float*)d_in[9];
  const float* saw  = (const float*)d_in[10]; const float* sab = (const float*)d_in[11];
  const float* sow  = (const float*)d_in[12]; const float* sob = (const float*)d_in[13];
  const float* ln1w = (const float*)d_in[14]; const float* ln1b = (const float*)d_in[15];
  const float* ln2w = (const float*)d_in[16]; const float* ln2b = (const float*)d_in[17];
  const float* ln3w = (const float*)d_in[18]; const float* ln3b = (const float*)d_in[19];
  const float* f1w  = (const float*)d_in[20]; const float* f1bs = (const float*)d_in[21];
  const float* f2w  = (const float*)d_in[22]; const float* f2bs = (const float*)d_in[23];

  char* base = (char*)d_ws;
  size_t off = 0;
  auto alloc = [&](size_t bytes) -> char* {
    char* p = base + off;
    off += (bytes + 255) & ~(size_t)255;
    return p;
  };
  u16* cw1b = (u16*)alloc(65536u*2);
  u16* cw2b = (u16*)alloc(65536u*2);
  u16* cw3b = (u16*)alloc(65536u*2);   (void)cw3b;
  u16* sawb = (u16*)alloc(196608u*2);
  u16* sowb = (u16*)alloc(65536u*2);
  u16* f1wb = (u16*)alloc(524288u*2);
  u16* f2wb = (u16*)alloc(524288u*2);
  int* rns  = (int*)alloc(4096u*32*4);
  float* cbKV = (float*)alloc(512*4);
  size_t offB = off;
  u16* xnh = (u16*)alloc((size_t)4096*256*2);
  u16* xnl = (u16*)alloc((size_t)4096*256*2);
  u16* mnh = (u16*)alloc((size_t)32768*256*2);
  u16* mnl = (u16*)alloc((size_t)32768*256*2);
  u16* qc  = (u16*)alloc((size_t)4096*256*2);
  u16* kc  = (u16*)alloc((size_t)32768*256*2);
  u16* vc  = (u16*)alloc((size_t)32768*256*2);
  float* sim = (float*)alloc((size_t)8*512*4096*4);

  char* regC = (char*)sim;
  u16* qh   = (u16*)regC;                      // [4096][256]  2 MB
  u16* khvh = (u16*)(regC + 2097152);          // [32768][512] 32 MB
  char* regB = base + offB;
  size_t ob = 0;
  auto allocB = [&](size_t bytes) -> char* {
    char* p = regB + ob;
    ob += (bytes + 255) & ~(size_t)255;
    return p;
  };
  float* cross = (float*)allocB((size_t)4096*256*4);
  float* t1    = (float*)allocB((size_t)4096*256*4);
  u16*   t1b   = (u16*)allocB((size_t)4096*256*2);
  u16*   qkb   = (u16*)allocB((size_t)4096*256*2);
  u16*   qkv   = (u16*)allocB((size_t)4096*768*2);
  u16*   sa_pre= (u16*)allocB((size_t)4096*256*2);
  float* sa    = (float*)allocB((size_t)4096*256*4);
  float* t2    = (float*)allocB((size_t)4096*256*4);
  u16*   t2b   = (u16*)allocB((size_t)4096*256*2);
  u16*   h1    = (u16*)allocB((size_t)4096*2048*2);
  float* ff    = (float*)allocB((size_t)4096*256*4);

  const int BIG = 1 << 30;
  dim3 blk(256);
  fused_prep<<<dim3(FP_TOT_B), blk, 0, stream>>>(
      mem, kpos, mnh, mnl, kc, vc,
      tgt, qpos, xnh, xnl, qc, cb2, cb3, cbKV,
      cw1, cw2, cw3, saw, sow, f1w, f2w, cw1b);
  sim_gemm<<<dim3(32,4,8), blk, 0, stream>>>(xnh, xnl, mnh, mnl, sim);
  topk_k<<<dim3(4096), blk, 0, stream>>>(sim, rns);
  pgemm<1,1,0><<<dim3(64,4), blk, 0, stream>>>(qc, qc, BIG, cw1b, cb1, qh, 256);
  pgemm<1,1,0><<<dim3(512,8), blk, 0, stream>>>(kc, vc, 256, cw2b, cbKV, khvh, 512);
  cross_attn<<<dim3(4096), blk, 0, stream>>>(qh, khvh, rns, cross);
  ln_k<1><<<dim3(4096), blk, 0, stream>>>(tgt, cross, qpos, ln1w, ln1b, t1, t1b, qkb);
  pgemm<1,1,0><<<dim3(64,12), blk, 0, stream>>>(qkb, t1b, 512, sawb, sab, qkv, 768);
  self_attn<<<dim3(16,8,8), blk, 0, stream>>>(qkv, sa_pre);
  pgemm<1,0,0><<<dim3(64,4), blk, 0, stream>>>(sa_pre, sa_pre, BIG, sowb, sob, sa, 256);
  ln_k<2><<<dim3(4096), blk, 0, stream>>>(t1, sa, nullptr, ln2w, ln2b, t2, t2b, nullptr);
  pgemm<1,1,1><<<dim3(64,32), blk, 0, stream>>>(t2b, t2b, BIG, f1wb, f1bs, h1, 2048);
  pgemm<8,0,0><<<dim3(64,4), blk, 0, stream>>>(h1, h1, BIG, f2wb, f2bs, ff, 256);
  ln_k<3><<<dim3(4096), blk, 0, stream>>>(t2, ff, nullptr, ln3w, ln3b, (float*)d_out, nullptr, nullptr);
}